// Round 6
// baseline (542.893 us; speedup 1.0000x reference)
//
#include <hip/hip_runtime.h>
#include <math.h>

// ---------------------------------------------------------------------------
// PixelCNN (5 gated residual blocks) + DMOL logprob.  Round 6:
//   - k_blk: 2 output rows per WG (640 thr, 10 waves). Each wave: M=32
//     (a-tile + b-gate tile), N=128 (both rows). Per k-iter: 2 global A-loads
//     feed 16 MFMAs -> 4x better latency hiding than r5; weight L2 traffic
//     halved vs r4 (256 MB/layer). 3 staged input rows shared by 2 out rows.
//   - h bf16 channel-last [b][y][x][160] single stream
//   - fast transcendentals + packed bf16 relu staging
// ---------------------------------------------------------------------------

using short8  = __attribute__((ext_vector_type(8))) short;
using short4v = __attribute__((ext_vector_type(4))) short;
using f32x4   = __attribute__((ext_vector_type(4))) float;

static constexpr float L2E = 1.44269504088896f;   // log2(e)
static constexpr float LN2 = 0.69314718055995f;   // ln(2)

__device__ __forceinline__ float fexp2(float x) { return __builtin_amdgcn_exp2f(x); }
__device__ __forceinline__ float flog2(float x) { return __builtin_amdgcn_logf(x); }
__device__ __forceinline__ float frcp(float x)  { return __builtin_amdgcn_rcpf(x); }
__device__ __forceinline__ float fexp(float x)  { return fexp2(x * L2E); }
__device__ __forceinline__ float flog(float x)  { return flog2(x) * LN2; }
__device__ __forceinline__ float fsigmoid(float x) { return frcp(1.f + fexp2(-x * L2E)); }
__device__ __forceinline__ float ftanh(float x)    { return 1.f - 2.f * frcp(1.f + fexp2(x * (2.f * L2E))); }
__device__ __forceinline__ float fsoftplus(float z) {
    float e = fexp2(-fabsf(z) * L2E);
    return fmaxf(z, 0.f) + flog2(1.f + e) * LN2;
}

// pack two fp32 -> packed bf16 pair (a low, b high)
__device__ __forceinline__ unsigned pk_bf16(float a, float b) {
    union { float f; unsigned u; } ua, ub; ua.f = a; ub.f = b;
    return __builtin_amdgcn_perm(ub.u + 0x7fffu, ua.u + 0x7fffu, 0x07060302u);
}

__device__ __forceinline__ short f2bf(float f) {
    union { float f; unsigned u; } v; v.f = f;
    unsigned r = (v.u + 0x7fffu + ((v.u >> 16) & 1u)) >> 16;
    return (short)r;
}

__device__ __forceinline__ float bf2f(unsigned short s) {
    union { unsigned u; float f; } v; v.u = ((unsigned)s) << 16; return v.f;
}

// packed relu on 2 bf16 halves of a u32
__device__ __forceinline__ unsigned relu2(unsigned v) {
    unsigned m = ((v & 0x80008000u) >> 15) * 0xffffu;
    return v & ~m;
}

// workspace layout (bytes), 16B-aligned
static constexpr size_t X_OFF    = 0;             // 16*3*4096*4    = 786432
static constexpr size_t WINP_OFF = 786432;        // 3*160*32*2     = 30720
static constexpr size_t W1P_OFF  = 817152;        // 5*160*32*2     = 51200
static constexpr size_t W2P_OFF  = 868352;        // 5*160*32*2     = 51200
static constexpr size_t WPB_OFF  = 919552;        // 5*25*320*32*2  = 2560000
static constexpr size_t HA_OFF   = 3479552;       // 16*4096*160*2  = 20971520
static constexpr size_t HB_OFF   = 24451072;      // 20971520 (end ~45.4 MB)

__global__ void k_prep(const float* __restrict__ s, float* __restrict__ x, int n) {
    int i = blockIdx.x * 256 + threadIdx.x;
    if (i < n) x[i] = 2.f * s[i] - 1.f;
}

// w_blk (5,320,160,3,3) -> bf16 wP[i][kt=tap*5+icb][oc320][icl32]
__global__ void k_twb(const float* __restrict__ w, short* __restrict__ wP) {
    int idx = blockIdx.x * 256 + threadIdx.x;
    if (idx >= 5 * 25 * 320 * 32) return;
    int icl = idx & 31;
    int oc  = (idx >> 5) % 320;
    int kt  = ((idx >> 5) / 320) % 25;
    int i   = idx / (25 * 320 * 32);
    int tap = kt / 5, ic = (kt % 5) * 32 + icl;
    const int ky[5] = {0,0,0,1,1}, kx[5] = {0,1,2,0,1};
    float v = w[(((size_t)(i * 320 + oc) * 160 + ic) * 3 + ky[tap]) * 3 + kx[tap]];
    wP[idx] = f2bf(v);
}

// w_in (160,3,7,7) -> WINP[kc3][oc160][icl32], k=tap*3+ic over 24 mask-A taps, pad 96
__global__ void k_twin(const float* __restrict__ w, short* __restrict__ wP) {
    int idx = blockIdx.x * 256 + threadIdx.x;
    if (idx >= 3 * 160 * 32) return;
    int icl = idx & 31;
    int oc  = (idx >> 5) % 160;
    int kc  = idx / 5120;
    int k = kc * 32 + icl;
    short v = 0;
    if (k < 72) {
        int tap = k / 3, ic = k % 3;
        int ky = (tap < 21) ? tap / 7 : 3;
        int kx = (tap < 21) ? tap % 7 : tap - 21;
        v = f2bf(w[((oc * 3 + ic) * 7 + ky) * 7 + kx]);
    }
    wP[idx] = v;
}

// w_out1 (160,160,1,1) -> W1P[kc5][oc160][icl32]
__global__ void k_tw1(const float* __restrict__ w, short* __restrict__ wP) {
    int idx = blockIdx.x * 256 + threadIdx.x;
    if (idx >= 5 * 160 * 32) return;
    int icl = idx & 31;
    int oc  = (idx >> 5) % 160;
    int kc  = idx / 5120;
    wP[idx] = f2bf(w[oc * 160 + kc * 32 + icl]);
}

// w_out2 (100,160,1,1) -> W2P[kc5][oc160 pad][icl32]
__global__ void k_tw2(const float* __restrict__ w, short* __restrict__ wP) {
    int idx = blockIdx.x * 256 + threadIdx.x;
    if (idx >= 5 * 160 * 32) return;
    int icl = idx & 31;
    int oc  = (idx >> 5) % 160;
    int kc  = idx / 5120;
    wP[idx] = (oc < 100) ? f2bf(w[oc * 160 + kc * 32 + icl]) : (short)0;
}

// masked 7x7 input conv, MFMA. grid (128,16) = (y*2+half, b), block 320 (5 waves).
__global__ __launch_bounds__(320) void k_convin(const float* __restrict__ X,
                                                const short* __restrict__ WINP,
                                                unsigned short* __restrict__ hout) {
    __shared__ float xls[3 * 4 * 40];   // [ic][r=ky][col 38], xg = xbase+col-3
    __shared__ short Bls[32 * 104];     // [px][k pad104]
    int y = blockIdx.x >> 1, half = blockIdx.x & 1, b = blockIdx.y;
    int xbase = half * 32;
    int t = threadIdx.x;
    for (int i = t; i < 456; i += 320) {
        int col = i % 38; int r = (i / 38) % 4; int ic = i / 152;
        int xg = xbase + col - 3, yg = y + r - 3;
        float v = 0.f;
        if (xg >= 0 && xg < 64 && yg >= 0)
            v = X[((size_t)(b * 3 + ic) * 64 + yg) * 64 + xg];
        xls[(ic * 4 + r) * 40 + col] = v;
    }
    __syncthreads();
    for (int i = t; i < 3072; i += 320) {
        int k = i % 96; int px = i / 96;
        short v = 0;
        if (k < 72) {
            int tap = k / 3, ic = k % 3;
            int ky = (tap < 21) ? tap / 7 : 3;
            int kx = (tap < 21) ? tap % 7 : tap - 21;
            v = f2bf(xls[(ic * 4 + ky) * 40 + px + kx]);
        }
        Bls[px * 104 + k] = v;
    }
    __syncthreads();
    int lane = t & 63, w = t >> 6;
    int lx = lane & 15, q = lane >> 4;
    f32x4 acc[2][2] = {};
    const short* wl = WINP + lx * 32 + q * 8;
    #pragma unroll
    for (int kc = 0; kc < 3; ++kc) {
        short8 aF[2], bF[2];
        aF[0] = *(const short8*)(wl + (kc * 160 + 32 * w) * 32);
        aF[1] = *(const short8*)(wl + (kc * 160 + 32 * w + 16) * 32);
        #pragma unroll
        for (int nt = 0; nt < 2; ++nt)
            bF[nt] = *(const short8*)&Bls[(nt * 16 + lx) * 104 + kc * 32 + q * 8];
        #pragma unroll
        for (int mt = 0; mt < 2; ++mt)
            #pragma unroll
            for (int nt = 0; nt < 2; ++nt)
                acc[mt][nt] = __builtin_amdgcn_mfma_f32_16x16x32_bf16(
                    aF[mt], bF[nt], acc[mt][nt], 0, 0, 0);
    }
    size_t rowbase = ((size_t)(b * 64 + y)) * 64 * 160;
    #pragma unroll
    for (int mt = 0; mt < 2; ++mt) {
        int c0 = 32 * w + mt * 16 + q * 4;
        #pragma unroll
        for (int nt = 0; nt < 2; ++nt) {
            int px = xbase + nt * 16 + lx;
            uint2 o;
            o.x = pk_bf16(acc[mt][nt][0], acc[mt][nt][1]);
            o.y = pk_bf16(acc[mt][nt][2], acc[mt][nt][3]);
            *(uint2*)&hout[rowbase + (size_t)px * 160 + c0] = o;
        }
    }
}

// MFMA gated block conv. grid (32,16) = (y0/2, b), block 640 (10 waves).
// Wave j: a-channels [16j,16j+16) + b-partners [160+16j,..); N=128 (rows y0,y0+1).
// Per k-iter: 2 global A-loads -> 16 MFMAs. 3 staged rows shared by 2 out rows.
__global__ __launch_bounds__(640) void k_blk(const unsigned short* __restrict__ hin,
                                             unsigned short* __restrict__ hout,
                                             const short* __restrict__ wP) {
    __shared__ short in_s[3 * 66 * 160];   // [r3][x 0..65][ic160] = 63360 B
    int y0 = blockIdx.x * 2, b = blockIdx.y;
    int t = threadIdx.x;
    // stage rows y0-1, y0, y0+1 (x halo, packed-int relu of bf16)
    for (int i = t; i < 3960; i += 640) {
        int c8 = i % 20; int xl = (i / 20) % 66; int r = i / 1320;
        int xg = xl - 1, yg = y0 + r - 1;
        uint4 v = {0u, 0u, 0u, 0u};
        if (xg >= 0 && xg < 64 && yg >= 0) {
            v = *(const uint4*)&hin[(((size_t)(b * 64 + yg)) * 64 + xg) * 160 + c8 * 8];
            v.x = relu2(v.x); v.y = relu2(v.y); v.z = relu2(v.z); v.w = relu2(v.w);
        }
        *(uint4*)&in_s[(r * 66 + xl) * 160 + c8 * 8] = v;
    }
    __syncthreads();

    int lane = t & 63, j = t >> 6;      // j = 0..9: oc16 slice
    int lx = lane & 15, q = lane >> 4;
    f32x4 acc[2][8] = {};               // [a/b gate][nt: row=nt>>2, px16=nt&3]
    const short* wl = wP + lx * 32 + q * 8;
    const int dxs[5] = {-1, 0, 1, -1, 0};
    const int rws[5] = {0, 0, 0, 1, 1};
    #pragma unroll
    for (int tap = 0; tap < 5; ++tap) {
        #pragma unroll
        for (int k5 = 0; k5 < 5; ++k5) {
            const short* wk = wl + (tap * 5 + k5) * 10240;
            short8 aF[2], bF[8];
            aF[0] = *(const short8*)(wk + (16 * j) * 32);
            aF[1] = *(const short8*)(wk + (160 + 16 * j) * 32);
            #pragma unroll
            for (int nt = 0; nt < 8; ++nt) {
                int rr = rws[tap] + (nt >> 2);
                int xc = 1 + dxs[tap] + (nt & 3) * 16 + lx;
                bF[nt] = *(const short8*)&in_s[(rr * 66 + xc) * 160 + k5 * 32 + q * 8];
            }
            #pragma unroll
            for (int mt = 0; mt < 2; ++mt)
                #pragma unroll
                for (int nt = 0; nt < 8; ++nt)
                    acc[mt][nt] = __builtin_amdgcn_mfma_f32_16x16x32_bf16(
                        aF[mt], bF[nt], acc[mt][nt], 0, 0, 0);
        }
    }
    // epilogue: gating + bf16 residual rmw (a=acc[0], b-gate=acc[1])
    int c0 = 16 * j + q * 4;
    #pragma unroll
    for (int nt = 0; nt < 8; ++nt) {
        int y = y0 + (nt >> 2);
        int px = (nt & 3) * 16 + lx;
        size_t off = (((size_t)(b * 64 + y)) * 64 + px) * 160 + c0;
        ushort4 hv = *(const ushort4*)&hin[off];
        float o0 = bf2f(hv.x) + ftanh(acc[0][nt][0]) * fsigmoid(acc[1][nt][0]);
        float o1 = bf2f(hv.y) + ftanh(acc[0][nt][1]) * fsigmoid(acc[1][nt][1]);
        float o2 = bf2f(hv.z) + ftanh(acc[0][nt][2]) * fsigmoid(acc[1][nt][2]);
        float o3 = bf2f(hv.w) + ftanh(acc[0][nt][3]) * fsigmoid(acc[1][nt][3]);
        uint2 o;
        o.x = pk_bf16(o0, o1);
        o.y = pk_bf16(o2, o3);
        *(uint2*)&hout[off] = o;
    }
}

// fused head: relu -> conv1x1(W1) -> relu -> conv1x1(W2) -> DMOL -> atomicAdd.
// grid (128,16) = (y*2+half, b), block 320 (5 waves). N=32 px.
__global__ __launch_bounds__(320) void k_head(const unsigned short* __restrict__ hin,
                                              const short* __restrict__ W1P,
                                              const short* __restrict__ W2P,
                                              const float* __restrict__ X,
                                              float* __restrict__ out) {
    __shared__ char arena[14848];         // hls(10752) aliased by Pls(13312)+lpls(1536)
    __shared__ short h2ls[32 * 168];      // 10752 B
    short* hls = (short*)arena;           // [px32][ic pad168] bf16 relu(h)
    float* Pls = (float*)arena;           // [px32][c pad104] fp32 params
    float* lpls = (float*)(arena + 13312);// [px32][m pad12]
    int y = blockIdx.x >> 1, half = blockIdx.x & 1, b = blockIdx.y;
    int xbase = half * 32;
    int t = threadIdx.x;
    size_t rowbase = ((size_t)(b * 64 + y)) * 64 * 160;
    for (int i = t; i < 640; i += 320) {
        int c8 = i % 20; int px = i / 20;
        uint4 v = *(const uint4*)&hin[rowbase + (size_t)(xbase + px) * 160 + c8 * 8];
        v.x = relu2(v.x); v.y = relu2(v.y); v.z = relu2(v.z); v.w = relu2(v.w);
        *(uint4*)&hls[px * 168 + c8 * 8] = v;
    }
    __syncthreads();
    int lane = t & 63, w = t >> 6;
    int lx = lane & 15, q = lane >> 4;
    // GEMM1: h2 = relu(W1 * relu(h))
    {
        f32x4 acc[2][2] = {};
        const short* wl = W1P + lx * 32 + q * 8;
        #pragma unroll
        for (int kc = 0; kc < 5; ++kc) {
            short8 aF[2], bF[2];
            aF[0] = *(const short8*)(wl + (kc * 160 + 32 * w) * 32);
            aF[1] = *(const short8*)(wl + (kc * 160 + 32 * w + 16) * 32);
            #pragma unroll
            for (int nt = 0; nt < 2; ++nt)
                bF[nt] = *(const short8*)&hls[(nt * 16 + lx) * 168 + kc * 32 + q * 8];
            #pragma unroll
            for (int mt = 0; mt < 2; ++mt)
                #pragma unroll
                for (int nt = 0; nt < 2; ++nt)
                    acc[mt][nt] = __builtin_amdgcn_mfma_f32_16x16x32_bf16(
                        aF[mt], bF[nt], acc[mt][nt], 0, 0, 0);
        }
        __syncthreads();   // hls reads done before Pls writes (alias)
        #pragma unroll
        for (int mt = 0; mt < 2; ++mt) {
            int c0 = 32 * w + mt * 16 + q * 4;
            #pragma unroll
            for (int nt = 0; nt < 2; ++nt) {
                int px = nt * 16 + lx;
                union { short4v s; unsigned u[2]; } sv;
                sv.u[0] = pk_bf16(fmaxf(acc[mt][nt][0], 0.f), fmaxf(acc[mt][nt][1], 0.f));
                sv.u[1] = pk_bf16(fmaxf(acc[mt][nt][2], 0.f), fmaxf(acc[mt][nt][3], 0.f));
                *(short4v*)&h2ls[px * 168 + c0] = sv.s;
            }
        }
    }
    __syncthreads();
    // GEMM2: params = W2 * h2 (oc padded to 160; only c<100 stored)
    {
        f32x4 acc[2][2] = {};
        const short* wl = W2P + lx * 32 + q * 8;
        #pragma unroll
        for (int kc = 0; kc < 5; ++kc) {
            short8 aF[2], bF[2];
            aF[0] = *(const short8*)(wl + (kc * 160 + 32 * w) * 32);
            aF[1] = *(const short8*)(wl + (kc * 160 + 32 * w + 16) * 32);
            #pragma unroll
            for (int nt = 0; nt < 2; ++nt)
                bF[nt] = *(const short8*)&h2ls[(nt * 16 + lx) * 168 + kc * 32 + q * 8];
            #pragma unroll
            for (int mt = 0; mt < 2; ++mt)
                #pragma unroll
                for (int nt = 0; nt < 2; ++nt)
                    acc[mt][nt] = __builtin_amdgcn_mfma_f32_16x16x32_bf16(
                        aF[mt], bF[nt], acc[mt][nt], 0, 0, 0);
        }
        #pragma unroll
        for (int mt = 0; mt < 2; ++mt) {
            int c0 = 32 * w + mt * 16 + q * 4;
            if (c0 < 100) {
                #pragma unroll
                for (int nt = 0; nt < 2; ++nt) {
                    int px = nt * 16 + lx;
                    float4 o;
                    o.x = acc[mt][nt][0]; o.y = acc[mt][nt][1];
                    o.z = acc[mt][nt][2]; o.w = acc[mt][nt][3];
                    *(float4*)&Pls[px * 104 + c0] = o;
                }
            }
        }
    }
    __syncthreads();
    // DMOL: 320 (px,m) tasks, one per thread
    const float LOG127P5 = 4.8481163504f;   // ln(127.5)
    {
        int px = t & 31, m = t >> 5;
        const float* pp = &Pls[px * 104];
        float xs[3];
        #pragma unroll
        for (int c = 0; c < 3; ++c)
            xs[c] = X[((size_t)(b * 3 + c)) * 4096 + (size_t)y * 64 + xbase + px];
        float mx = pp[0];
        #pragma unroll
        for (int j = 1; j < 10; ++j) mx = fmaxf(mx, pp[j]);
        float se = 0.f;
        #pragma unroll
        for (int j = 0; j < 10; ++j) se += fexp(pp[j] - mx);
        float lse = mx + flog(se);
        float sum = pp[m] - lse;
        float mean0 = pp[10 + m];
        float mean1 = pp[40 + m];
        float mean2 = pp[70 + m];
        float ls0 = fmaxf(pp[20 + m], -7.f);
        float ls1 = fmaxf(pp[50 + m], -7.f);
        float ls2 = fmaxf(pp[80 + m], -7.f);
        float c0 = ftanh(pp[30 + m]);
        float c1 = ftanh(pp[60 + m]);
        float c2 = ftanh(pp[90 + m]);
        float mu[3], lsv[3];
        mu[0] = mean0;
        mu[1] = mean1 + c0 * xs[0];
        mu[2] = mean2 + c1 * xs[0] + c2 * xs[1];
        lsv[0] = ls0; lsv[1] = ls1; lsv[2] = ls2;
        #pragma unroll
        for (int ci = 0; ci < 3; ++ci) {
            float cent = xs[ci] - mu[ci];
            float inv = fexp(-lsv[ci]);
            float plus_in = inv * (cent + 1.f / 255.f);
            float min_in = inv * (cent - 1.f / 255.f);
            float cdf_delta = fsigmoid(plus_in) - fsigmoid(min_in);
            float log_cdf_plus = plus_in - fsoftplus(plus_in);
            float log_om_cdf = -fsoftplus(min_in);
            float mid = inv * cent;
            float log_pdf_mid = mid - lsv[ci] - 2.f * fsoftplus(mid);
            float lpi = (cdf_delta > 1e-5f) ? flog(fmaxf(cdf_delta, 1e-12f))
                                            : (log_pdf_mid - LOG127P5);
            float lpc = (xs[ci] < -0.999f) ? log_cdf_plus
                       : ((xs[ci] > 0.999f) ? log_om_cdf : lpi);
            sum += lpc;
        }
        lpls[px * 12 + m] = sum;
    }
    __syncthreads();
    if (t < 32) {
        int px = t;
        float mx2 = lpls[px * 12];
        #pragma unroll
        for (int m = 1; m < 10; ++m) mx2 = fmaxf(mx2, lpls[px * 12 + m]);
        float se2 = 0.f;
        #pragma unroll
        for (int m = 0; m < 10; ++m) se2 += fexp(lpls[px * 12 + m] - mx2);
        float lp = mx2 + flog(se2);
        lp += __shfl_down(lp, 16, 32);
        lp += __shfl_down(lp, 8, 32);
        lp += __shfl_down(lp, 4, 32);
        lp += __shfl_down(lp, 2, 32);
        lp += __shfl_down(lp, 1, 32);
        if (t == 0) atomicAdd(&out[b], lp);
    }
}

extern "C" void kernel_launch(void* const* d_in, const int* in_sizes, int n_in,
                              void* d_out, int out_size, void* d_ws, size_t ws_size,
                              hipStream_t stream) {
    const float* samples = (const float*)d_in[0];
    const float* w_in    = (const float*)d_in[1];
    const float* w_blk   = (const float*)d_in[2];
    const float* w_out1  = (const float*)d_in[3];
    const float* w_out2  = (const float*)d_in[4];
    char* ws = (char*)d_ws;
    float* X    = (float*)(ws + X_OFF);
    short* WINP = (short*)(ws + WINP_OFF);
    short* W1P  = (short*)(ws + W1P_OFF);
    short* W2P  = (short*)(ws + W2P_OFF);
    short* WPB  = (short*)(ws + WPB_OFF);
    unsigned short* HA = (unsigned short*)(ws + HA_OFF);
    unsigned short* HB = (unsigned short*)(ws + HB_OFF);
    float* fout = (float*)d_out;

    k_prep<<<768, 256, 0, stream>>>(samples, X, 16 * 3 * 4096);
    k_twb<<<5000, 256, 0, stream>>>(w_blk, WPB);
    k_twin<<<60, 256, 0, stream>>>(w_in, WINP);
    k_tw1<<<100, 256, 0, stream>>>(w_out1, W1P);
    k_tw2<<<100, 256, 0, stream>>>(w_out2, W2P);

    k_convin<<<dim3(128, 16), 320, 0, stream>>>(X, WINP, HA);

    unsigned short* a = HA; unsigned short* bq = HB;
    for (int i = 0; i < 5; i++) {
        k_blk<<<dim3(32, 16), 640, 0, stream>>>(a, bq, WPB + (size_t)i * 25 * 320 * 32);
        unsigned short* tmp = a; a = bq; bq = tmp;
    }
    hipMemsetAsync(d_out, 0, (size_t)out_size * sizeof(float), stream);
    k_head<<<dim3(128, 16), 320, 0, stream>>>(a, W1P, W2P, X, fout);
}

// Round 7
// 464.703 us; speedup vs baseline: 1.1683x; 1.1683x over previous
//
#include <hip/hip_runtime.h>
#include <math.h>

// ---------------------------------------------------------------------------
// PixelCNN (5 gated residual blocks) + DMOL logprob.  Round 7:
//   - k_blk: r4 wave shape (M=64/wave = 32 a-ch + 32 b-gates, clean 64B-line
//     epilogue) x 2 output rows per WG (N=128/wave). 5 waves, grid (32,16).
//     Per k-iter: 4 global A-loads -> 32 MFMAs; weight L2 traffic 256 MB/layer
//     (half of r4, without r6's 16-ch write amplification).
//   - h bf16 channel-last [b][y][x][160] single stream
//   - fast transcendentals + packed bf16 relu staging
// ---------------------------------------------------------------------------

using short8  = __attribute__((ext_vector_type(8))) short;
using short4v = __attribute__((ext_vector_type(4))) short;
using f32x4   = __attribute__((ext_vector_type(4))) float;

static constexpr float L2E = 1.44269504088896f;   // log2(e)
static constexpr float LN2 = 0.69314718055995f;   // ln(2)

__device__ __forceinline__ float fexp2(float x) { return __builtin_amdgcn_exp2f(x); }
__device__ __forceinline__ float flog2(float x) { return __builtin_amdgcn_logf(x); }
__device__ __forceinline__ float frcp(float x)  { return __builtin_amdgcn_rcpf(x); }
__device__ __forceinline__ float fexp(float x)  { return fexp2(x * L2E); }
__device__ __forceinline__ float flog(float x)  { return flog2(x) * LN2; }
__device__ __forceinline__ float fsigmoid(float x) { return frcp(1.f + fexp2(-x * L2E)); }
__device__ __forceinline__ float ftanh(float x)    { return 1.f - 2.f * frcp(1.f + fexp2(x * (2.f * L2E))); }
__device__ __forceinline__ float fsoftplus(float z) {
    float e = fexp2(-fabsf(z) * L2E);
    return fmaxf(z, 0.f) + flog2(1.f + e) * LN2;
}

// pack two fp32 -> packed bf16 pair (a low, b high)
__device__ __forceinline__ unsigned pk_bf16(float a, float b) {
    union { float f; unsigned u; } ua, ub; ua.f = a; ub.f = b;
    return __builtin_amdgcn_perm(ub.u + 0x7fffu, ua.u + 0x7fffu, 0x07060302u);
}

__device__ __forceinline__ short f2bf(float f) {
    union { float f; unsigned u; } v; v.f = f;
    unsigned r = (v.u + 0x7fffu + ((v.u >> 16) & 1u)) >> 16;
    return (short)r;
}

__device__ __forceinline__ float bf2f(unsigned short s) {
    union { unsigned u; float f; } v; v.u = ((unsigned)s) << 16; return v.f;
}

// packed relu on 2 bf16 halves of a u32
__device__ __forceinline__ unsigned relu2(unsigned v) {
    unsigned m = ((v & 0x80008000u) >> 15) * 0xffffu;
    return v & ~m;
}

// workspace layout (bytes), 16B-aligned
static constexpr size_t X_OFF    = 0;             // 16*3*4096*4    = 786432
static constexpr size_t WINP_OFF = 786432;        // 3*160*32*2     = 30720
static constexpr size_t W1P_OFF  = 817152;        // 5*160*32*2     = 51200
static constexpr size_t W2P_OFF  = 868352;        // 5*160*32*2     = 51200
static constexpr size_t WPB_OFF  = 919552;        // 5*25*320*32*2  = 2560000
static constexpr size_t HA_OFF   = 3479552;       // 16*4096*160*2  = 20971520
static constexpr size_t HB_OFF   = 24451072;      // 20971520 (end ~45.4 MB)

__global__ void k_prep(const float* __restrict__ s, float* __restrict__ x, int n) {
    int i = blockIdx.x * 256 + threadIdx.x;
    if (i < n) x[i] = 2.f * s[i] - 1.f;
}

// w_blk (5,320,160,3,3) -> bf16 wP[i][kt=tap*5+icb][oc320][icl32]
__global__ void k_twb(const float* __restrict__ w, short* __restrict__ wP) {
    int idx = blockIdx.x * 256 + threadIdx.x;
    if (idx >= 5 * 25 * 320 * 32) return;
    int icl = idx & 31;
    int oc  = (idx >> 5) % 320;
    int kt  = ((idx >> 5) / 320) % 25;
    int i   = idx / (25 * 320 * 32);
    int tap = kt / 5, ic = (kt % 5) * 32 + icl;
    const int ky[5] = {0,0,0,1,1}, kx[5] = {0,1,2,0,1};
    float v = w[(((size_t)(i * 320 + oc) * 160 + ic) * 3 + ky[tap]) * 3 + kx[tap]];
    wP[idx] = f2bf(v);
}

// w_in (160,3,7,7) -> WINP[kc3][oc160][icl32], k=tap*3+ic over 24 mask-A taps, pad 96
__global__ void k_twin(const float* __restrict__ w, short* __restrict__ wP) {
    int idx = blockIdx.x * 256 + threadIdx.x;
    if (idx >= 3 * 160 * 32) return;
    int icl = idx & 31;
    int oc  = (idx >> 5) % 160;
    int kc  = idx / 5120;
    int k = kc * 32 + icl;
    short v = 0;
    if (k < 72) {
        int tap = k / 3, ic = k % 3;
        int ky = (tap < 21) ? tap / 7 : 3;
        int kx = (tap < 21) ? tap % 7 : tap - 21;
        v = f2bf(w[((oc * 3 + ic) * 7 + ky) * 7 + kx]);
    }
    wP[idx] = v;
}

// w_out1 (160,160,1,1) -> W1P[kc5][oc160][icl32]
__global__ void k_tw1(const float* __restrict__ w, short* __restrict__ wP) {
    int idx = blockIdx.x * 256 + threadIdx.x;
    if (idx >= 5 * 160 * 32) return;
    int icl = idx & 31;
    int oc  = (idx >> 5) % 160;
    int kc  = idx / 5120;
    wP[idx] = f2bf(w[oc * 160 + kc * 32 + icl]);
}

// w_out2 (100,160,1,1) -> W2P[kc5][oc160 pad][icl32]
__global__ void k_tw2(const float* __restrict__ w, short* __restrict__ wP) {
    int idx = blockIdx.x * 256 + threadIdx.x;
    if (idx >= 5 * 160 * 32) return;
    int icl = idx & 31;
    int oc  = (idx >> 5) % 160;
    int kc  = idx / 5120;
    wP[idx] = (oc < 100) ? f2bf(w[oc * 160 + kc * 32 + icl]) : (short)0;
}

// masked 7x7 input conv, MFMA. grid (128,16) = (y*2+half, b), block 320 (5 waves).
__global__ __launch_bounds__(320) void k_convin(const float* __restrict__ X,
                                                const short* __restrict__ WINP,
                                                unsigned short* __restrict__ hout) {
    __shared__ float xls[3 * 4 * 40];   // [ic][r=ky][col 38], xg = xbase+col-3
    __shared__ short Bls[32 * 104];     // [px][k pad104]
    int y = blockIdx.x >> 1, half = blockIdx.x & 1, b = blockIdx.y;
    int xbase = half * 32;
    int t = threadIdx.x;
    for (int i = t; i < 456; i += 320) {
        int col = i % 38; int r = (i / 38) % 4; int ic = i / 152;
        int xg = xbase + col - 3, yg = y + r - 3;
        float v = 0.f;
        if (xg >= 0 && xg < 64 && yg >= 0)
            v = X[((size_t)(b * 3 + ic) * 64 + yg) * 64 + xg];
        xls[(ic * 4 + r) * 40 + col] = v;
    }
    __syncthreads();
    for (int i = t; i < 3072; i += 320) {
        int k = i % 96; int px = i / 96;
        short v = 0;
        if (k < 72) {
            int tap = k / 3, ic = k % 3;
            int ky = (tap < 21) ? tap / 7 : 3;
            int kx = (tap < 21) ? tap % 7 : tap - 21;
            v = f2bf(xls[(ic * 4 + ky) * 40 + px + kx]);
        }
        Bls[px * 104 + k] = v;
    }
    __syncthreads();
    int lane = t & 63, w = t >> 6;
    int lx = lane & 15, q = lane >> 4;
    f32x4 acc[2][2] = {};
    const short* wl = WINP + lx * 32 + q * 8;
    #pragma unroll
    for (int kc = 0; kc < 3; ++kc) {
        short8 aF[2], bF[2];
        aF[0] = *(const short8*)(wl + (kc * 160 + 32 * w) * 32);
        aF[1] = *(const short8*)(wl + (kc * 160 + 32 * w + 16) * 32);
        #pragma unroll
        for (int nt = 0; nt < 2; ++nt)
            bF[nt] = *(const short8*)&Bls[(nt * 16 + lx) * 104 + kc * 32 + q * 8];
        #pragma unroll
        for (int mt = 0; mt < 2; ++mt)
            #pragma unroll
            for (int nt = 0; nt < 2; ++nt)
                acc[mt][nt] = __builtin_amdgcn_mfma_f32_16x16x32_bf16(
                    aF[mt], bF[nt], acc[mt][nt], 0, 0, 0);
    }
    size_t rowbase = ((size_t)(b * 64 + y)) * 64 * 160;
    #pragma unroll
    for (int mt = 0; mt < 2; ++mt) {
        int c0 = 32 * w + mt * 16 + q * 4;
        #pragma unroll
        for (int nt = 0; nt < 2; ++nt) {
            int px = xbase + nt * 16 + lx;
            uint2 o;
            o.x = pk_bf16(acc[mt][nt][0], acc[mt][nt][1]);
            o.y = pk_bf16(acc[mt][nt][2], acc[mt][nt][3]);
            *(uint2*)&hout[rowbase + (size_t)px * 160 + c0] = o;
        }
    }
}

// MFMA gated block conv. grid (32,16) = (y0/2, b), block 320 (10 half... 5 waves).
// Wave w: a-channels [32w,32w+32) + b-partners [160+32w,..); N=128 (rows y0,y0+1).
// Per k-iter: 4 global A-loads -> 32 MFMAs. 3 staged rows shared by 2 out rows.
__global__ __launch_bounds__(320, 2) void k_blk(const unsigned short* __restrict__ hin,
                                                unsigned short* __restrict__ hout,
                                                const short* __restrict__ wP) {
    __shared__ short in_s[3 * 66 * 160];   // [r3][x 0..65][ic160] = 63360 B
    int y0 = blockIdx.x * 2, b = blockIdx.y;
    int t = threadIdx.x;
    // stage rows y0-1, y0, y0+1 (x halo, packed-int relu of bf16)
    for (int i = t; i < 3960; i += 320) {
        int c8 = i % 20; int xl = (i / 20) % 66; int r = i / 1320;
        int xg = xl - 1, yg = y0 + r - 1;
        uint4 v = {0u, 0u, 0u, 0u};
        if (xg >= 0 && xg < 64 && yg >= 0) {
            v = *(const uint4*)&hin[(((size_t)(b * 64 + yg)) * 64 + xg) * 160 + c8 * 8];
            v.x = relu2(v.x); v.y = relu2(v.y); v.z = relu2(v.z); v.w = relu2(v.w);
        }
        *(uint4*)&in_s[(r * 66 + xl) * 160 + c8 * 8] = v;
    }
    __syncthreads();

    int lane = t & 63, w = t >> 6;      // w = 0..4: 32-channel a/b slice
    int lx = lane & 15, q = lane >> 4;
    f32x4 acc[4][8] = {};               // [mt: a0,a1,b0,b1][nt: row=nt>>2, px16=nt&3]
    const short* wl = wP + lx * 32 + q * 8;
    const int dxs[5] = {-1, 0, 1, -1, 0};
    const int rws[5] = {0, 0, 0, 1, 1};
    #pragma unroll
    for (int tap = 0; tap < 5; ++tap) {
        #pragma unroll
        for (int k5 = 0; k5 < 5; ++k5) {
            const short* wk = wl + (tap * 5 + k5) * 10240;
            short8 aF[4];
            aF[0] = *(const short8*)(wk + (32 * w) * 32);
            aF[1] = *(const short8*)(wk + (32 * w + 16) * 32);
            aF[2] = *(const short8*)(wk + (160 + 32 * w) * 32);
            aF[3] = *(const short8*)(wk + (176 + 32 * w) * 32);
            #pragma unroll
            for (int nt = 0; nt < 8; ++nt) {
                int rr = rws[tap] + (nt >> 2);
                int xc = 1 + dxs[tap] + (nt & 3) * 16 + lx;
                short8 bF = *(const short8*)&in_s[(rr * 66 + xc) * 160 + k5 * 32 + q * 8];
                #pragma unroll
                for (int mt = 0; mt < 4; ++mt)
                    acc[mt][nt] = __builtin_amdgcn_mfma_f32_16x16x32_bf16(
                        aF[mt], bF, acc[mt][nt], 0, 0, 0);
            }
        }
    }
    // epilogue: gating + bf16 residual rmw (a=acc[mt], b-gate=acc[mt+2])
    #pragma unroll
    for (int mt = 0; mt < 2; ++mt) {
        int c0 = 32 * w + mt * 16 + q * 4;
        #pragma unroll
        for (int nt = 0; nt < 8; ++nt) {
            int y = y0 + (nt >> 2);
            int px = (nt & 3) * 16 + lx;
            size_t off = (((size_t)(b * 64 + y)) * 64 + px) * 160 + c0;
            ushort4 hv = *(const ushort4*)&hin[off];
            float o0 = bf2f(hv.x) + ftanh(acc[mt][nt][0]) * fsigmoid(acc[mt + 2][nt][0]);
            float o1 = bf2f(hv.y) + ftanh(acc[mt][nt][1]) * fsigmoid(acc[mt + 2][nt][1]);
            float o2 = bf2f(hv.z) + ftanh(acc[mt][nt][2]) * fsigmoid(acc[mt + 2][nt][2]);
            float o3 = bf2f(hv.w) + ftanh(acc[mt][nt][3]) * fsigmoid(acc[mt + 2][nt][3]);
            uint2 o;
            o.x = pk_bf16(o0, o1);
            o.y = pk_bf16(o2, o3);
            *(uint2*)&hout[off] = o;
        }
    }
}

// fused head: relu -> conv1x1(W1) -> relu -> conv1x1(W2) -> DMOL -> atomicAdd.
// grid (128,16) = (y*2+half, b), block 320 (5 waves). N=32 px.
__global__ __launch_bounds__(320) void k_head(const unsigned short* __restrict__ hin,
                                              const short* __restrict__ W1P,
                                              const short* __restrict__ W2P,
                                              const float* __restrict__ X,
                                              float* __restrict__ out) {
    __shared__ char arena[14848];         // hls(10752) aliased by Pls(13312)+lpls(1536)
    __shared__ short h2ls[32 * 168];      // 10752 B
    short* hls = (short*)arena;           // [px32][ic pad168] bf16 relu(h)
    float* Pls = (float*)arena;           // [px32][c pad104] fp32 params
    float* lpls = (float*)(arena + 13312);// [px32][m pad12]
    int y = blockIdx.x >> 1, half = blockIdx.x & 1, b = blockIdx.y;
    int xbase = half * 32;
    int t = threadIdx.x;
    size_t rowbase = ((size_t)(b * 64 + y)) * 64 * 160;
    for (int i = t; i < 640; i += 320) {
        int c8 = i % 20; int px = i / 20;
        uint4 v = *(const uint4*)&hin[rowbase + (size_t)(xbase + px) * 160 + c8 * 8];
        v.x = relu2(v.x); v.y = relu2(v.y); v.z = relu2(v.z); v.w = relu2(v.w);
        *(uint4*)&hls[px * 168 + c8 * 8] = v;
    }
    __syncthreads();
    int lane = t & 63, w = t >> 6;
    int lx = lane & 15, q = lane >> 4;
    // GEMM1: h2 = relu(W1 * relu(h))
    {
        f32x4 acc[2][2] = {};
        const short* wl = W1P + lx * 32 + q * 8;
        #pragma unroll
        for (int kc = 0; kc < 5; ++kc) {
            short8 aF[2], bF[2];
            aF[0] = *(const short8*)(wl + (kc * 160 + 32 * w) * 32);
            aF[1] = *(const short8*)(wl + (kc * 160 + 32 * w + 16) * 32);
            #pragma unroll
            for (int nt = 0; nt < 2; ++nt)
                bF[nt] = *(const short8*)&hls[(nt * 16 + lx) * 168 + kc * 32 + q * 8];
            #pragma unroll
            for (int mt = 0; mt < 2; ++mt)
                #pragma unroll
                for (int nt = 0; nt < 2; ++nt)
                    acc[mt][nt] = __builtin_amdgcn_mfma_f32_16x16x32_bf16(
                        aF[mt], bF[nt], acc[mt][nt], 0, 0, 0);
        }
        __syncthreads();   // hls reads done before Pls writes (alias)
        #pragma unroll
        for (int mt = 0; mt < 2; ++mt) {
            int c0 = 32 * w + mt * 16 + q * 4;
            #pragma unroll
            for (int nt = 0; nt < 2; ++nt) {
                int px = nt * 16 + lx;
                union { short4v s; unsigned u[2]; } sv;
                sv.u[0] = pk_bf16(fmaxf(acc[mt][nt][0], 0.f), fmaxf(acc[mt][nt][1], 0.f));
                sv.u[1] = pk_bf16(fmaxf(acc[mt][nt][2], 0.f), fmaxf(acc[mt][nt][3], 0.f));
                *(short4v*)&h2ls[px * 168 + c0] = sv.s;
            }
        }
    }
    __syncthreads();
    // GEMM2: params = W2 * h2 (oc padded to 160; only c<100 stored)
    {
        f32x4 acc[2][2] = {};
        const short* wl = W2P + lx * 32 + q * 8;
        #pragma unroll
        for (int kc = 0; kc < 5; ++kc) {
            short8 aF[2], bF[2];
            aF[0] = *(const short8*)(wl + (kc * 160 + 32 * w) * 32);
            aF[1] = *(const short8*)(wl + (kc * 160 + 32 * w + 16) * 32);
            #pragma unroll
            for (int nt = 0; nt < 2; ++nt)
                bF[nt] = *(const short8*)&h2ls[(nt * 16 + lx) * 168 + kc * 32 + q * 8];
            #pragma unroll
            for (int mt = 0; mt < 2; ++mt)
                #pragma unroll
                for (int nt = 0; nt < 2; ++nt)
                    acc[mt][nt] = __builtin_amdgcn_mfma_f32_16x16x32_bf16(
                        aF[mt], bF[nt], acc[mt][nt], 0, 0, 0);
        }
        #pragma unroll
        for (int mt = 0; mt < 2; ++mt) {
            int c0 = 32 * w + mt * 16 + q * 4;
            if (c0 < 100) {
                #pragma unroll
                for (int nt = 0; nt < 2; ++nt) {
                    int px = nt * 16 + lx;
                    float4 o;
                    o.x = acc[mt][nt][0]; o.y = acc[mt][nt][1];
                    o.z = acc[mt][nt][2]; o.w = acc[mt][nt][3];
                    *(float4*)&Pls[px * 104 + c0] = o;
                }
            }
        }
    }
    __syncthreads();
    // DMOL: 320 (px,m) tasks, one per thread
    const float LOG127P5 = 4.8481163504f;   // ln(127.5)
    {
        int px = t & 31, m = t >> 5;
        const float* pp = &Pls[px * 104];
        float xs[3];
        #pragma unroll
        for (int c = 0; c < 3; ++c)
            xs[c] = X[((size_t)(b * 3 + c)) * 4096 + (size_t)y * 64 + xbase + px];
        float mx = pp[0];
        #pragma unroll
        for (int j = 1; j < 10; ++j) mx = fmaxf(mx, pp[j]);
        float se = 0.f;
        #pragma unroll
        for (int j = 0; j < 10; ++j) se += fexp(pp[j] - mx);
        float lse = mx + flog(se);
        float sum = pp[m] - lse;
        float mean0 = pp[10 + m];
        float mean1 = pp[40 + m];
        float mean2 = pp[70 + m];
        float ls0 = fmaxf(pp[20 + m], -7.f);
        float ls1 = fmaxf(pp[50 + m], -7.f);
        float ls2 = fmaxf(pp[80 + m], -7.f);
        float c0 = ftanh(pp[30 + m]);
        float c1 = ftanh(pp[60 + m]);
        float c2 = ftanh(pp[90 + m]);
        float mu[3], lsv[3];
        mu[0] = mean0;
        mu[1] = mean1 + c0 * xs[0];
        mu[2] = mean2 + c1 * xs[0] + c2 * xs[1];
        lsv[0] = ls0; lsv[1] = ls1; lsv[2] = ls2;
        #pragma unroll
        for (int ci = 0; ci < 3; ++ci) {
            float cent = xs[ci] - mu[ci];
            float inv = fexp(-lsv[ci]);
            float plus_in = inv * (cent + 1.f / 255.f);
            float min_in = inv * (cent - 1.f / 255.f);
            float cdf_delta = fsigmoid(plus_in) - fsigmoid(min_in);
            float log_cdf_plus = plus_in - fsoftplus(plus_in);
            float log_om_cdf = -fsoftplus(min_in);
            float mid = inv * cent;
            float log_pdf_mid = mid - lsv[ci] - 2.f * fsoftplus(mid);
            float lpi = (cdf_delta > 1e-5f) ? flog(fmaxf(cdf_delta, 1e-12f))
                                            : (log_pdf_mid - LOG127P5);
            float lpc = (xs[ci] < -0.999f) ? log_cdf_plus
                       : ((xs[ci] > 0.999f) ? log_om_cdf : lpi);
            sum += lpc;
        }
        lpls[px * 12 + m] = sum;
    }
    __syncthreads();
    if (t < 32) {
        int px = t;
        float mx2 = lpls[px * 12];
        #pragma unroll
        for (int m = 1; m < 10; ++m) mx2 = fmaxf(mx2, lpls[px * 12 + m]);
        float se2 = 0.f;
        #pragma unroll
        for (int m = 0; m < 10; ++m) se2 += fexp(lpls[px * 12 + m] - mx2);
        float lp = mx2 + flog(se2);
        lp += __shfl_down(lp, 16, 32);
        lp += __shfl_down(lp, 8, 32);
        lp += __shfl_down(lp, 4, 32);
        lp += __shfl_down(lp, 2, 32);
        lp += __shfl_down(lp, 1, 32);
        if (t == 0) atomicAdd(&out[b], lp);
    }
}

extern "C" void kernel_launch(void* const* d_in, const int* in_sizes, int n_in,
                              void* d_out, int out_size, void* d_ws, size_t ws_size,
                              hipStream_t stream) {
    const float* samples = (const float*)d_in[0];
    const float* w_in    = (const float*)d_in[1];
    const float* w_blk   = (const float*)d_in[2];
    const float* w_out1  = (const float*)d_in[3];
    const float* w_out2  = (const float*)d_in[4];
    char* ws = (char*)d_ws;
    float* X    = (float*)(ws + X_OFF);
    short* WINP = (short*)(ws + WINP_OFF);
    short* W1P  = (short*)(ws + W1P_OFF);
    short* W2P  = (short*)(ws + W2P_OFF);
    short* WPB  = (short*)(ws + WPB_OFF);
    unsigned short* HA = (unsigned short*)(ws + HA_OFF);
    unsigned short* HB = (unsigned short*)(ws + HB_OFF);
    float* fout = (float*)d_out;

    k_prep<<<768, 256, 0, stream>>>(samples, X, 16 * 3 * 4096);
    k_twb<<<5000, 256, 0, stream>>>(w_blk, WPB);
    k_twin<<<60, 256, 0, stream>>>(w_in, WINP);
    k_tw1<<<100, 256, 0, stream>>>(w_out1, W1P);
    k_tw2<<<100, 256, 0, stream>>>(w_out2, W2P);

    k_convin<<<dim3(128, 16), 320, 0, stream>>>(X, WINP, HA);

    unsigned short* a = HA; unsigned short* bq = HB;
    for (int i = 0; i < 5; i++) {
        k_blk<<<dim3(32, 16), 320, 0, stream>>>(a, bq, WPB + (size_t)i * 25 * 320 * 32);
        unsigned short* tmp = a; a = bq; bq = tmp;
    }
    hipMemsetAsync(d_out, 0, (size_t)out_size * sizeof(float), stream);
    k_head<<<dim3(128, 16), 320, 0, stream>>>(a, W1P, W2P, X, fout);
}

// Round 8
// 461.106 us; speedup vs baseline: 1.1774x; 1.0078x over previous
//
#include <hip/hip_runtime.h>
#include <math.h>

// ---------------------------------------------------------------------------
// PixelCNN (5 gated residual blocks) + DMOL logprob.  Round 8:
//   - k_blk: 32x32x16 MFMA (half the instrs/LDS reads of 16x16x32),
//     grid (64,16), 5 waves, M=64/wave (32 a + 32 gate), N=64.
//   - dual h streams: h bf16 CL (residual) + hrelu bf16 halo-padded
//     [b][yp65][xp66][168] -> staging is a contiguous 44KB copy via
//     __builtin_amdgcn_global_load_lds (width 16, no VALU roundtrip).
//   - halos pre-zeroed once per call (k_halo); pad 168 = 16B-aligned b128.
//   - fast transcendentals for gating + DMOL.
// ---------------------------------------------------------------------------

using short8  = __attribute__((ext_vector_type(8))) short;
using short4v = __attribute__((ext_vector_type(4))) short;
using f32x4   = __attribute__((ext_vector_type(4))) float;
using f32x16  = __attribute__((ext_vector_type(16))) float;

static constexpr float L2E = 1.44269504088896f;   // log2(e)
static constexpr float LN2 = 0.69314718055995f;   // ln(2)

// hrelu padded layout: [b][yp 0..64][xp 0..65][168]; yp=y+1, xp=x+1
static constexpr int CPAD = 168;
static constexpr int RST  = 66 * CPAD;       // 11088 elem per padded row
static constexpr int IST  = 65 * RST;        // 720720 elem per image

__device__ __forceinline__ float fexp2(float x) { return __builtin_amdgcn_exp2f(x); }
__device__ __forceinline__ float flog2(float x) { return __builtin_amdgcn_logf(x); }
__device__ __forceinline__ float frcp(float x)  { return __builtin_amdgcn_rcpf(x); }
__device__ __forceinline__ float fexp(float x)  { return fexp2(x * L2E); }
__device__ __forceinline__ float flog(float x)  { return flog2(x) * LN2; }
__device__ __forceinline__ float fsigmoid(float x) { return frcp(1.f + fexp2(-x * L2E)); }
__device__ __forceinline__ float ftanh(float x)    { return 1.f - 2.f * frcp(1.f + fexp2(x * (2.f * L2E))); }
__device__ __forceinline__ float fsoftplus(float z) {
    float e = fexp2(-fabsf(z) * L2E);
    return fmaxf(z, 0.f) + flog2(1.f + e) * LN2;
}

__device__ __forceinline__ unsigned pk_bf16(float a, float b) {
    union { float f; unsigned u; } ua, ub; ua.f = a; ub.f = b;
    return __builtin_amdgcn_perm(ub.u + 0x7fffu, ua.u + 0x7fffu, 0x07060302u);
}

__device__ __forceinline__ short f2bf(float f) {
    union { float f; unsigned u; } v; v.f = f;
    unsigned r = (v.u + 0x7fffu + ((v.u >> 16) & 1u)) >> 16;
    return (short)r;
}

__device__ __forceinline__ float bf2f(unsigned short s) {
    union { unsigned u; float f; } v; v.u = ((unsigned)s) << 16; return v.f;
}

// workspace layout (bytes), 16B-aligned
static constexpr size_t X_OFF    = 0;              // 16*3*4096*4     = 786432
static constexpr size_t WINP_OFF = 786432;         // 3*160*32*2      = 30720
static constexpr size_t W1P_OFF  = 817152;         // 5*160*32*2      = 51200
static constexpr size_t W2P_OFF  = 868352;         // 5*160*32*2      = 51200
static constexpr size_t WPB_OFF  = 919552;         // 5*100*320*8*2   = 2560000
static constexpr size_t HA_OFF   = 3479552;        // 16*4096*160*2   = 20971520
static constexpr size_t HB_OFF   = 24451072;       // 20971520
static constexpr size_t HRA_OFF  = 45422592;       // 16*IST*2        = 23063040
static constexpr size_t HRB_OFF  = 68485632;       // 23063040 (end ~91.5 MB)

__global__ void k_prep(const float* __restrict__ s, float* __restrict__ x, int n) {
    int i = blockIdx.x * 256 + threadIdx.x;
    if (i < n) x[i] = 2.f * s[i] - 1.f;
}

// w_blk (5,320,160,3,3) -> wP[i][sp=s*2+pair (0..99)][oc320][8], bf16
// mapping: k = s*16 + pair*8 + j; tap = k/160; ic = k%160
__global__ void k_twb(const float* __restrict__ w, short* __restrict__ wP) {
    int idx = blockIdx.x * 256 + threadIdx.x;
    if (idx >= 5 * 100 * 320 * 8) return;
    int j  = idx & 7;
    int r  = idx >> 3;
    int oc = r % 320;
    int r2 = r / 320;
    int sp = r2 % 100;
    int i  = r2 / 100;
    int s = sp >> 1, pair = sp & 1;
    int k = s * 16 + pair * 8 + j;
    int tap = k / 160, ic = k - tap * 160;
    const int ky[5] = {0,0,0,1,1}, kx[5] = {0,1,2,0,1};
    float v = w[(((size_t)(i * 320 + oc) * 160 + ic) * 3 + ky[tap]) * 3 + kx[tap]];
    wP[idx] = f2bf(v);
}

// w_in (160,3,7,7) -> WINP[kc3][oc160][icl32], k=tap*3+ic over 24 mask-A taps, pad 96
__global__ void k_twin(const float* __restrict__ w, short* __restrict__ wP) {
    int idx = blockIdx.x * 256 + threadIdx.x;
    if (idx >= 3 * 160 * 32) return;
    int icl = idx & 31;
    int oc  = (idx >> 5) % 160;
    int kc  = idx / 5120;
    int k = kc * 32 + icl;
    short v = 0;
    if (k < 72) {
        int tap = k / 3, ic = k % 3;
        int ky = (tap < 21) ? tap / 7 : 3;
        int kx = (tap < 21) ? tap % 7 : tap - 21;
        v = f2bf(w[((oc * 3 + ic) * 7 + ky) * 7 + kx]);
    }
    wP[idx] = v;
}

// w_out1 (160,160,1,1) -> W1P[kc5][oc160][icl32]
__global__ void k_tw1(const float* __restrict__ w, short* __restrict__ wP) {
    int idx = blockIdx.x * 256 + threadIdx.x;
    if (idx >= 5 * 160 * 32) return;
    int icl = idx & 31;
    int oc  = (idx >> 5) % 160;
    int kc  = idx / 5120;
    wP[idx] = f2bf(w[oc * 160 + kc * 32 + icl]);
}

// w_out2 (100,160,1,1) -> W2P[kc5][oc160 pad][icl32]
__global__ void k_tw2(const float* __restrict__ w, short* __restrict__ wP) {
    int idx = blockIdx.x * 256 + threadIdx.x;
    if (idx >= 5 * 160 * 32) return;
    int icl = idx & 31;
    int oc  = (idx >> 5) % 160;
    int kc  = idx / 5120;
    wP[idx] = (oc < 100) ? f2bf(w[oc * 160 + kc * 32 + icl]) : (short)0;
}

// zero hrelu halos (yp=0 full row; xp=0 and xp=65 for yp>=1) for both buffers
__global__ void k_halo(unsigned short* __restrict__ hrA, unsigned short* __restrict__ hrB) {
    int i = blockIdx.x * 256 + threadIdx.x;
    if (i >= 16 * 194 * CPAD) return;
    int c = i % CPAD;
    int r = (i / CPAD) % 194;
    int b = i / (CPAD * 194);
    int yp, xp;
    if (r < 66) { yp = 0; xp = r; }
    else { int rr = r - 66; yp = 1 + (rr >> 1); xp = (rr & 1) ? 65 : 0; }
    unsigned short* p = blockIdx.y ? hrB : hrA;
    p[((size_t)b * 65 + yp) * RST + (size_t)xp * CPAD + c] = 0;
}

// masked 7x7 input conv, MFMA 16x16. grid (128,16) = (y*2+half, b), block 320.
// Writes h bf16 CL + hrelu padded.
__global__ __launch_bounds__(320) void k_convin(const float* __restrict__ X,
                                                const short* __restrict__ WINP,
                                                unsigned short* __restrict__ hout,
                                                unsigned short* __restrict__ hrout) {
    __shared__ float xls[3 * 4 * 40];
    __shared__ short Bls[32 * 104];
    int y = blockIdx.x >> 1, half = blockIdx.x & 1, b = blockIdx.y;
    int xbase = half * 32;
    int t = threadIdx.x;
    for (int i = t; i < 456; i += 320) {
        int col = i % 38; int r = (i / 38) % 4; int ic = i / 152;
        int xg = xbase + col - 3, yg = y + r - 3;
        float v = 0.f;
        if (xg >= 0 && xg < 64 && yg >= 0)
            v = X[((size_t)(b * 3 + ic) * 64 + yg) * 64 + xg];
        xls[(ic * 4 + r) * 40 + col] = v;
    }
    __syncthreads();
    for (int i = t; i < 3072; i += 320) {
        int k = i % 96; int px = i / 96;
        short v = 0;
        if (k < 72) {
            int tap = k / 3, ic = k % 3;
            int ky = (tap < 21) ? tap / 7 : 3;
            int kx = (tap < 21) ? tap % 7 : tap - 21;
            v = f2bf(xls[(ic * 4 + ky) * 40 + px + kx]);
        }
        Bls[px * 104 + k] = v;
    }
    __syncthreads();
    int lane = t & 63, w = t >> 6;
    int lx = lane & 15, q = lane >> 4;
    f32x4 acc[2][2] = {};
    const short* wl = WINP + lx * 32 + q * 8;
    #pragma unroll
    for (int kc = 0; kc < 3; ++kc) {
        short8 aF[2], bF[2];
        aF[0] = *(const short8*)(wl + (kc * 160 + 32 * w) * 32);
        aF[1] = *(const short8*)(wl + (kc * 160 + 32 * w + 16) * 32);
        #pragma unroll
        for (int nt = 0; nt < 2; ++nt)
            bF[nt] = *(const short8*)&Bls[(nt * 16 + lx) * 104 + kc * 32 + q * 8];
        #pragma unroll
        for (int mt = 0; mt < 2; ++mt)
            #pragma unroll
            for (int nt = 0; nt < 2; ++nt)
                acc[mt][nt] = __builtin_amdgcn_mfma_f32_16x16x32_bf16(
                    aF[mt], bF[nt], acc[mt][nt], 0, 0, 0);
    }
    size_t rowbase = ((size_t)(b * 64 + y)) * 64 * 160;
    size_t rbase   = ((size_t)b * 65 + (y + 1)) * RST;
    #pragma unroll
    for (int mt = 0; mt < 2; ++mt) {
        int c0 = 32 * w + mt * 16 + q * 4;
        #pragma unroll
        for (int nt = 0; nt < 2; ++nt) {
            int px = xbase + nt * 16 + lx;
            float o0 = acc[mt][nt][0], o1 = acc[mt][nt][1];
            float o2 = acc[mt][nt][2], o3 = acc[mt][nt][3];
            uint2 oh;
            oh.x = pk_bf16(o0, o1); oh.y = pk_bf16(o2, o3);
            *(uint2*)&hout[rowbase + (size_t)px * 160 + c0] = oh;
            uint2 orr;
            orr.x = pk_bf16(fmaxf(o0, 0.f), fmaxf(o1, 0.f));
            orr.y = pk_bf16(fmaxf(o2, 0.f), fmaxf(o3, 0.f));
            *(uint2*)&hrout[rbase + (size_t)(px + 1) * CPAD + c0] = orr;
        }
    }
}

// MFMA gated block conv, 32x32x16. grid (64,16) = (y,b), block 320 (5 waves).
// Wave w: m-tile0 = a-ch [32w,32w+32), m-tile1 = gate-ch [160+32w, ..). N=64.
__global__ __launch_bounds__(320, 4) void k_blk(const unsigned short* __restrict__ h_in,
                                                unsigned short* __restrict__ h_out,
                                                const unsigned short* __restrict__ hr_in,
                                                unsigned short* __restrict__ hr_out,
                                                const short* __restrict__ wP) {
    __shared__ short in_s[2 * RST];   // rows yp=y, y+1 (data y-1, y) = 44352 B
    int y = blockIdx.x, b = blockIdx.y;
    int t = threadIdx.x;
    int lane = t & 63, w = t >> 6;
    // async contiguous copy: hrelu rows yp=y .. y+1 (2*11088 elem = 2772 x 16B)
    {
        const unsigned short* src = hr_in + ((size_t)b * 65 + y) * RST;
        #pragma unroll
        for (int r = 0; r < 9; ++r) {
            int cb = __builtin_amdgcn_readfirstlane(r * 320 + w * 64);
            if (cb + lane < 2772) {
                __builtin_amdgcn_global_load_lds(
                    (const __attribute__((address_space(1))) unsigned int*)(src + (size_t)(cb + lane) * 8),
                    (__attribute__((address_space(3))) unsigned int*)(in_s + cb * 8),
                    16, 0, 0);
            }
        }
    }
    __syncthreads();

    int lm = lane & 31, pair = lane >> 5;
    f32x16 acc[2][2] = {};   // [a/gate][n-tile]
    const short* waP = wP + pair * 2560 + (32 * w + lm) * 8;
    const int dxs[5] = {-1, 0, 1, -1, 0};
    const int rws[5] = {0, 0, 0, 1, 1};
    #pragma unroll
    for (int tap = 0; tap < 5; ++tap) {
        int rb0 = (rws[tap] * 66 + 1 + dxs[tap] + lm) * CPAD + pair * 8;
        #pragma unroll
        for (int si = 0; si < 10; ++si) {
            int s = tap * 10 + si;
            short8 aA = *(const short8*)(waP + (size_t)s * 5120);
            short8 aG = *(const short8*)(waP + 1280 + (size_t)s * 5120);
            short8 b0 = *(const short8*)&in_s[rb0 + si * 16];
            short8 b1 = *(const short8*)&in_s[rb0 + 32 * CPAD + si * 16];
            acc[0][0] = __builtin_amdgcn_mfma_f32_32x32x16_bf16(aA, b0, acc[0][0], 0, 0, 0);
            acc[0][1] = __builtin_amdgcn_mfma_f32_32x32x16_bf16(aA, b1, acc[0][1], 0, 0, 0);
            acc[1][0] = __builtin_amdgcn_mfma_f32_32x32x16_bf16(aG, b0, acc[1][0], 0, 0, 0);
            acc[1][1] = __builtin_amdgcn_mfma_f32_32x32x16_bf16(aG, b1, acc[1][1], 0, 0, 0);
        }
    }
    // epilogue: C layout col=lane&31(px), row=(reg&3)+8*(reg>>2)+4*pair (oc)
    size_t rowbase = ((size_t)(b * 64 + y)) * 64 * 160;
    size_t rbase   = ((size_t)b * 65 + (y + 1)) * RST;
    #pragma unroll
    for (int n = 0; n < 2; ++n) {
        int px = n * 32 + lm;
        #pragma unroll
        for (int qd = 0; qd < 4; ++qd) {
            int c0 = 32 * w + qd * 8 + 4 * pair;
            size_t offh = rowbase + (size_t)px * 160 + c0;
            ushort4 hv = *(const ushort4*)&h_in[offh];
            float o0 = bf2f(hv.x) + ftanh(acc[0][n][qd * 4 + 0]) * fsigmoid(acc[1][n][qd * 4 + 0]);
            float o1 = bf2f(hv.y) + ftanh(acc[0][n][qd * 4 + 1]) * fsigmoid(acc[1][n][qd * 4 + 1]);
            float o2 = bf2f(hv.z) + ftanh(acc[0][n][qd * 4 + 2]) * fsigmoid(acc[1][n][qd * 4 + 2]);
            float o3 = bf2f(hv.w) + ftanh(acc[0][n][qd * 4 + 3]) * fsigmoid(acc[1][n][qd * 4 + 3]);
            uint2 oh;
            oh.x = pk_bf16(o0, o1); oh.y = pk_bf16(o2, o3);
            *(uint2*)&h_out[offh] = oh;
            uint2 orr;
            orr.x = pk_bf16(fmaxf(o0, 0.f), fmaxf(o1, 0.f));
            orr.y = pk_bf16(fmaxf(o2, 0.f), fmaxf(o3, 0.f));
            *(uint2*)&hr_out[rbase + (size_t)(px + 1) * CPAD + c0] = orr;
        }
    }
}

// fused head: conv1x1(W1)+relu -> conv1x1(W2) -> DMOL -> atomicAdd.
// grid (128,16) = (y*2+half, b), block 320. Reads hrelu (already relu'd).
__global__ __launch_bounds__(320) void k_head(const unsigned short* __restrict__ hr,
                                              const short* __restrict__ W1P,
                                              const short* __restrict__ W2P,
                                              const float* __restrict__ X,
                                              float* __restrict__ out) {
    __shared__ char arena[14848];         // hls(10752) aliased by Pls(13312)+lpls(1536)
    __shared__ short h2ls[32 * 168];
    short* hls = (short*)arena;           // [px32][ic pad168] bf16 relu(h)
    float* Pls = (float*)arena;           // [px32][c pad104] fp32 params
    float* lpls = (float*)(arena + 13312);// [px32][m pad12]
    int y = blockIdx.x >> 1, half = blockIdx.x & 1, b = blockIdx.y;
    int xbase = half * 32;
    int t = threadIdx.x;
    size_t rbase = ((size_t)b * 65 + (y + 1)) * RST;
    for (int i = t; i < 640; i += 320) {
        int c8 = i % 20; int px = i / 20;
        uint4 v = *(const uint4*)&hr[rbase + (size_t)(xbase + px + 1) * CPAD + c8 * 8];
        *(uint4*)&hls[px * 168 + c8 * 8] = v;
    }
    __syncthreads();
    int lane = t & 63, w = t >> 6;
    int lx = lane & 15, q = lane >> 4;
    // GEMM1: h2 = relu(W1 * hrelu)
    {
        f32x4 acc[2][2] = {};
        const short* wl = W1P + lx * 32 + q * 8;
        #pragma unroll
        for (int kc = 0; kc < 5; ++kc) {
            short8 aF[2], bF[2];
            aF[0] = *(const short8*)(wl + (kc * 160 + 32 * w) * 32);
            aF[1] = *(const short8*)(wl + (kc * 160 + 32 * w + 16) * 32);
            #pragma unroll
            for (int nt = 0; nt < 2; ++nt)
                bF[nt] = *(const short8*)&hls[(nt * 16 + lx) * 168 + kc * 32 + q * 8];
            #pragma unroll
            for (int mt = 0; mt < 2; ++mt)
                #pragma unroll
                for (int nt = 0; nt < 2; ++nt)
                    acc[mt][nt] = __builtin_amdgcn_mfma_f32_16x16x32_bf16(
                        aF[mt], bF[nt], acc[mt][nt], 0, 0, 0);
        }
        __syncthreads();   // hls reads done before Pls writes (alias)
        #pragma unroll
        for (int mt = 0; mt < 2; ++mt) {
            int c0 = 32 * w + mt * 16 + q * 4;
            #pragma unroll
            for (int nt = 0; nt < 2; ++nt) {
                int px = nt * 16 + lx;
                union { short4v s; unsigned u[2]; } sv;
                sv.u[0] = pk_bf16(fmaxf(acc[mt][nt][0], 0.f), fmaxf(acc[mt][nt][1], 0.f));
                sv.u[1] = pk_bf16(fmaxf(acc[mt][nt][2], 0.f), fmaxf(acc[mt][nt][3], 0.f));
                *(short4v*)&h2ls[px * 168 + c0] = sv.s;
            }
        }
    }
    __syncthreads();
    // GEMM2: params = W2 * h2
    {
        f32x4 acc[2][2] = {};
        const short* wl = W2P + lx * 32 + q * 8;
        #pragma unroll
        for (int kc = 0; kc < 5; ++kc) {
            short8 aF[2], bF[2];
            aF[0] = *(const short8*)(wl + (kc * 160 + 32 * w) * 32);
            aF[1] = *(const short8*)(wl + (kc * 160 + 32 * w + 16) * 32);
            #pragma unroll
            for (int nt = 0; nt < 2; ++nt)
                bF[nt] = *(const short8*)&h2ls[(nt * 16 + lx) * 168 + kc * 32 + q * 8];
            #pragma unroll
            for (int mt = 0; mt < 2; ++mt)
                #pragma unroll
                for (int nt = 0; nt < 2; ++nt)
                    acc[mt][nt] = __builtin_amdgcn_mfma_f32_16x16x32_bf16(
                        aF[mt], bF[nt], acc[mt][nt], 0, 0, 0);
        }
        #pragma unroll
        for (int mt = 0; mt < 2; ++mt) {
            int c0 = 32 * w + mt * 16 + q * 4;
            if (c0 < 100) {
                #pragma unroll
                for (int nt = 0; nt < 2; ++nt) {
                    int px = nt * 16 + lx;
                    float4 o;
                    o.x = acc[mt][nt][0]; o.y = acc[mt][nt][1];
                    o.z = acc[mt][nt][2]; o.w = acc[mt][nt][3];
                    *(float4*)&Pls[px * 104 + c0] = o;
                }
            }
        }
    }
    __syncthreads();
    // DMOL: 320 (px,m) tasks
    const float LOG127P5 = 4.8481163504f;
    {
        int px = t & 31, m = t >> 5;
        const float* pp = &Pls[px * 104];
        float xs[3];
        #pragma unroll
        for (int c = 0; c < 3; ++c)
            xs[c] = X[((size_t)(b * 3 + c)) * 4096 + (size_t)y * 64 + xbase + px];
        float mx = pp[0];
        #pragma unroll
        for (int j = 1; j < 10; ++j) mx = fmaxf(mx, pp[j]);
        float se = 0.f;
        #pragma unroll
        for (int j = 0; j < 10; ++j) se += fexp(pp[j] - mx);
        float lse = mx + flog(se);
        float sum = pp[m] - lse;
        float mean0 = pp[10 + m];
        float mean1 = pp[40 + m];
        float mean2 = pp[70 + m];
        float ls0 = fmaxf(pp[20 + m], -7.f);
        float ls1 = fmaxf(pp[50 + m], -7.f);
        float ls2 = fmaxf(pp[80 + m], -7.f);
        float c0 = ftanh(pp[30 + m]);
        float c1 = ftanh(pp[60 + m]);
        float c2 = ftanh(pp[90 + m]);
        float mu[3], lsv[3];
        mu[0] = mean0;
        mu[1] = mean1 + c0 * xs[0];
        mu[2] = mean2 + c1 * xs[0] + c2 * xs[1];
        lsv[0] = ls0; lsv[1] = ls1; lsv[2] = ls2;
        #pragma unroll
        for (int ci = 0; ci < 3; ++ci) {
            float cent = xs[ci] - mu[ci];
            float inv = fexp(-lsv[ci]);
            float plus_in = inv * (cent + 1.f / 255.f);
            float min_in = inv * (cent - 1.f / 255.f);
            float cdf_delta = fsigmoid(plus_in) - fsigmoid(min_in);
            float log_cdf_plus = plus_in - fsoftplus(plus_in);
            float log_om_cdf = -fsoftplus(min_in);
            float mid = inv * cent;
            float log_pdf_mid = mid - lsv[ci] - 2.f * fsoftplus(mid);
            float lpi = (cdf_delta > 1e-5f) ? flog(fmaxf(cdf_delta, 1e-12f))
                                            : (log_pdf_mid - LOG127P5);
            float lpc = (xs[ci] < -0.999f) ? log_cdf_plus
                       : ((xs[ci] > 0.999f) ? log_om_cdf : lpi);
            sum += lpc;
        }
        lpls[px * 12 + m] = sum;
    }
    __syncthreads();
    if (t < 32) {
        int px = t;
        float mx2 = lpls[px * 12];
        #pragma unroll
        for (int m = 1; m < 10; ++m) mx2 = fmaxf(mx2, lpls[px * 12 + m]);
        float se2 = 0.f;
        #pragma unroll
        for (int m = 0; m < 10; ++m) se2 += fexp(lpls[px * 12 + m] - mx2);
        float lp = mx2 + flog(se2);
        lp += __shfl_down(lp, 16, 32);
        lp += __shfl_down(lp, 8, 32);
        lp += __shfl_down(lp, 4, 32);
        lp += __shfl_down(lp, 2, 32);
        lp += __shfl_down(lp, 1, 32);
        if (t == 0) atomicAdd(&out[b], lp);
    }
}

extern "C" void kernel_launch(void* const* d_in, const int* in_sizes, int n_in,
                              void* d_out, int out_size, void* d_ws, size_t ws_size,
                              hipStream_t stream) {
    const float* samples = (const float*)d_in[0];
    const float* w_in    = (const float*)d_in[1];
    const float* w_blk   = (const float*)d_in[2];
    const float* w_out1  = (const float*)d_in[3];
    const float* w_out2  = (const float*)d_in[4];
    char* ws = (char*)d_ws;
    float* X    = (float*)(ws + X_OFF);
    short* WINP = (short*)(ws + WINP_OFF);
    short* W1P  = (short*)(ws + W1P_OFF);
    short* W2P  = (short*)(ws + W2P_OFF);
    short* WPB  = (short*)(ws + WPB_OFF);
    unsigned short* HA  = (unsigned short*)(ws + HA_OFF);
    unsigned short* HB  = (unsigned short*)(ws + HB_OFF);
    unsigned short* HRA = (unsigned short*)(ws + HRA_OFF);
    unsigned short* HRB = (unsigned short*)(ws + HRB_OFF);
    float* fout = (float*)d_out;

    k_prep<<<768, 256, 0, stream>>>(samples, X, 16 * 3 * 4096);
    k_twb<<<5000, 256, 0, stream>>>(w_blk, WPB);
    k_twin<<<60, 256, 0, stream>>>(w_in, WINP);
    k_tw1<<<100, 256, 0, stream>>>(w_out1, W1P);
    k_tw2<<<100, 256, 0, stream>>>(w_out2, W2P);
    k_halo<<<dim3((16 * 194 * CPAD + 255) / 256, 2), 256, 0, stream>>>(HRA, HRB);

    k_convin<<<dim3(128, 16), 320, 0, stream>>>(X, WINP, HA, HRA);

    unsigned short* a = HA;  unsigned short* bq = HB;
    unsigned short* ra = HRA; unsigned short* rb = HRB;
    for (int i = 0; i < 5; i++) {
        k_blk<<<dim3(64, 16), 320, 0, stream>>>(a, bq, ra, rb, WPB + (size_t)i * 256000);
        unsigned short* tmp = a; a = bq; bq = tmp;
        unsigned short* tr = ra; ra = rb; rb = tr;
    }
    hipMemsetAsync(d_out, 0, (size_t)out_size * sizeof(float), stream);
    k_head<<<dim3(128, 16), 320, 0, stream>>>(ra, W1P, W2P, X, fout);
}

// Round 9
// 459.240 us; speedup vs baseline: 1.1822x; 1.0041x over previous
//
#include <hip/hip_runtime.h>
#include <math.h>

// ---------------------------------------------------------------------------
// PixelCNN (5 gated residual blocks) + DMOL logprob.  Round 9:
//   r8 structure (32x32x16 MFMA, dual h/hrelu bf16 streams, async LDS staging)
//   + per-wave tap rotation (decorrelate phase-locked load stalls)
//   + launch_bounds(320,3) reg headroom + manual depth-1 A prefetch
//   + epilogue residual reads prefetched before the k-loop
//   + k_prep fused into convin/head (2s-1 inline)
// ---------------------------------------------------------------------------

using short8  = __attribute__((ext_vector_type(8))) short;
using short4v = __attribute__((ext_vector_type(4))) short;
using f32x4   = __attribute__((ext_vector_type(4))) float;
using f32x16  = __attribute__((ext_vector_type(16))) float;

static constexpr float L2E = 1.44269504088896f;   // log2(e)
static constexpr float LN2 = 0.69314718055995f;   // ln(2)

// hrelu padded layout: [b][yp 0..64][xp 0..65][168]; yp=y+1, xp=x+1
static constexpr int CPAD = 168;
static constexpr int RST  = 66 * CPAD;       // 11088 elem per padded row
static constexpr int IST  = 65 * RST;        // 720720 elem per image

__device__ __forceinline__ float fexp2(float x) { return __builtin_amdgcn_exp2f(x); }
__device__ __forceinline__ float flog2(float x) { return __builtin_amdgcn_logf(x); }
__device__ __forceinline__ float frcp(float x)  { return __builtin_amdgcn_rcpf(x); }
__device__ __forceinline__ float fexp(float x)  { return fexp2(x * L2E); }
__device__ __forceinline__ float flog(float x)  { return flog2(x) * LN2; }
__device__ __forceinline__ float fsigmoid(float x) { return frcp(1.f + fexp2(-x * L2E)); }
__device__ __forceinline__ float ftanh(float x)    { return 1.f - 2.f * frcp(1.f + fexp2(x * (2.f * L2E))); }
__device__ __forceinline__ float fsoftplus(float z) {
    float e = fexp2(-fabsf(z) * L2E);
    return fmaxf(z, 0.f) + flog2(1.f + e) * LN2;
}

__device__ __forceinline__ unsigned pk_bf16(float a, float b) {
    union { float f; unsigned u; } ua, ub; ua.f = a; ub.f = b;
    return __builtin_amdgcn_perm(ub.u + 0x7fffu, ua.u + 0x7fffu, 0x07060302u);
}

__device__ __forceinline__ short f2bf(float f) {
    union { float f; unsigned u; } v; v.f = f;
    unsigned r = (v.u + 0x7fffu + ((v.u >> 16) & 1u)) >> 16;
    return (short)r;
}

__device__ __forceinline__ float bf2f(unsigned short s) {
    union { unsigned u; float f; } v; v.u = ((unsigned)s) << 16; return v.f;
}

// workspace layout (bytes), 16B-aligned
static constexpr size_t WINP_OFF = 0;              // 3*160*32*2      = 30720
static constexpr size_t W1P_OFF  = 30720;          // 5*160*32*2      = 51200
static constexpr size_t W2P_OFF  = 81920;          // 5*160*32*2      = 51200
static constexpr size_t WPB_OFF  = 133120;         // 5*100*320*8*2   = 2560000
static constexpr size_t HA_OFF   = 2693120;        // 16*4096*160*2   = 20971520
static constexpr size_t HB_OFF   = 23664640;       // 20971520
static constexpr size_t HRA_OFF  = 44636160;       // 16*IST*2        = 23063040
static constexpr size_t HRB_OFF  = 67699200;       // 23063040 (end ~90.8 MB)

// w_blk (5,320,160,3,3) -> wP[i][sp=s*2+pair (0..99)][oc320][8], bf16
// mapping: k = s*16 + pair*8 + j; tap = k/160; ic = k%160
__global__ void k_twb(const float* __restrict__ w, short* __restrict__ wP) {
    int idx = blockIdx.x * 256 + threadIdx.x;
    if (idx >= 5 * 100 * 320 * 8) return;
    int j  = idx & 7;
    int r  = idx >> 3;
    int oc = r % 320;
    int r2 = r / 320;
    int sp = r2 % 100;
    int i  = r2 / 100;
    int s = sp >> 1, pair = sp & 1;
    int k = s * 16 + pair * 8 + j;
    int tap = k / 160, ic = k - tap * 160;
    const int ky[5] = {0,0,0,1,1}, kx[5] = {0,1,2,0,1};
    float v = w[(((size_t)(i * 320 + oc) * 160 + ic) * 3 + ky[tap]) * 3 + kx[tap]];
    wP[idx] = f2bf(v);
}

// w_in (160,3,7,7) -> WINP[kc3][oc160][icl32], k=tap*3+ic over 24 mask-A taps, pad 96
__global__ void k_twin(const float* __restrict__ w, short* __restrict__ wP) {
    int idx = blockIdx.x * 256 + threadIdx.x;
    if (idx >= 3 * 160 * 32) return;
    int icl = idx & 31;
    int oc  = (idx >> 5) % 160;
    int kc  = idx / 5120;
    int k = kc * 32 + icl;
    short v = 0;
    if (k < 72) {
        int tap = k / 3, ic = k % 3;
        int ky = (tap < 21) ? tap / 7 : 3;
        int kx = (tap < 21) ? tap % 7 : tap - 21;
        v = f2bf(w[((oc * 3 + ic) * 7 + ky) * 7 + kx]);
    }
    wP[idx] = v;
}

// w_out1 (160,160,1,1) -> W1P[kc5][oc160][icl32]
__global__ void k_tw1(const float* __restrict__ w, short* __restrict__ wP) {
    int idx = blockIdx.x * 256 + threadIdx.x;
    if (idx >= 5 * 160 * 32) return;
    int icl = idx & 31;
    int oc  = (idx >> 5) % 160;
    int kc  = idx / 5120;
    wP[idx] = f2bf(w[oc * 160 + kc * 32 + icl]);
}

// w_out2 (100,160,1,1) -> W2P[kc5][oc160 pad][icl32]
__global__ void k_tw2(const float* __restrict__ w, short* __restrict__ wP) {
    int idx = blockIdx.x * 256 + threadIdx.x;
    if (idx >= 5 * 160 * 32) return;
    int icl = idx & 31;
    int oc  = (idx >> 5) % 160;
    int kc  = idx / 5120;
    wP[idx] = (oc < 100) ? f2bf(w[oc * 160 + kc * 32 + icl]) : (short)0;
}

// zero hrelu halos (yp=0 full row; xp=0 and xp=65 for yp>=1) for both buffers
__global__ void k_halo(unsigned short* __restrict__ hrA, unsigned short* __restrict__ hrB) {
    int i = blockIdx.x * 256 + threadIdx.x;
    if (i >= 16 * 194 * CPAD) return;
    int c = i % CPAD;
    int r = (i / CPAD) % 194;
    int b = i / (CPAD * 194);
    int yp, xp;
    if (r < 66) { yp = 0; xp = r; }
    else { int rr = r - 66; yp = 1 + (rr >> 1); xp = (rr & 1) ? 65 : 0; }
    unsigned short* p = blockIdx.y ? hrB : hrA;
    p[((size_t)b * 65 + yp) * RST + (size_t)xp * CPAD + c] = 0;
}

// masked 7x7 input conv, MFMA 16x16. grid (128,16) = (y*2+half, b), block 320.
// Reads samples directly (2s-1 inline). Writes h bf16 CL + hrelu padded.
__global__ __launch_bounds__(320) void k_convin(const float* __restrict__ S,
                                                const short* __restrict__ WINP,
                                                unsigned short* __restrict__ hout,
                                                unsigned short* __restrict__ hrout) {
    __shared__ float xls[3 * 4 * 40];
    __shared__ short Bls[32 * 104];
    int y = blockIdx.x >> 1, half = blockIdx.x & 1, b = blockIdx.y;
    int xbase = half * 32;
    int t = threadIdx.x;
    for (int i = t; i < 456; i += 320) {
        int col = i % 38; int r = (i / 38) % 4; int ic = i / 152;
        int xg = xbase + col - 3, yg = y + r - 3;
        float v = 0.f;
        if (xg >= 0 && xg < 64 && yg >= 0)
            v = 2.f * S[((size_t)(b * 3 + ic) * 64 + yg) * 64 + xg] - 1.f;
        xls[(ic * 4 + r) * 40 + col] = v;
    }
    __syncthreads();
    for (int i = t; i < 3072; i += 320) {
        int k = i % 96; int px = i / 96;
        short v = 0;
        if (k < 72) {
            int tap = k / 3, ic = k % 3;
            int ky = (tap < 21) ? tap / 7 : 3;
            int kx = (tap < 21) ? tap % 7 : tap - 21;
            v = f2bf(xls[(ic * 4 + ky) * 40 + px + kx]);
        }
        Bls[px * 104 + k] = v;
    }
    __syncthreads();
    int lane = t & 63, w = t >> 6;
    int lx = lane & 15, q = lane >> 4;
    f32x4 acc[2][2] = {};
    const short* wl = WINP + lx * 32 + q * 8;
    #pragma unroll
    for (int kc = 0; kc < 3; ++kc) {
        short8 aF[2], bF[2];
        aF[0] = *(const short8*)(wl + (kc * 160 + 32 * w) * 32);
        aF[1] = *(const short8*)(wl + (kc * 160 + 32 * w + 16) * 32);
        #pragma unroll
        for (int nt = 0; nt < 2; ++nt)
            bF[nt] = *(const short8*)&Bls[(nt * 16 + lx) * 104 + kc * 32 + q * 8];
        #pragma unroll
        for (int mt = 0; mt < 2; ++mt)
            #pragma unroll
            for (int nt = 0; nt < 2; ++nt)
                acc[mt][nt] = __builtin_amdgcn_mfma_f32_16x16x32_bf16(
                    aF[mt], bF[nt], acc[mt][nt], 0, 0, 0);
    }
    size_t rowbase = ((size_t)(b * 64 + y)) * 64 * 160;
    size_t rbase   = ((size_t)b * 65 + (y + 1)) * RST;
    #pragma unroll
    for (int mt = 0; mt < 2; ++mt) {
        int c0 = 32 * w + mt * 16 + q * 4;
        #pragma unroll
        for (int nt = 0; nt < 2; ++nt) {
            int px = xbase + nt * 16 + lx;
            float o0 = acc[mt][nt][0], o1 = acc[mt][nt][1];
            float o2 = acc[mt][nt][2], o3 = acc[mt][nt][3];
            uint2 oh;
            oh.x = pk_bf16(o0, o1); oh.y = pk_bf16(o2, o3);
            *(uint2*)&hout[rowbase + (size_t)px * 160 + c0] = oh;
            uint2 orr;
            orr.x = pk_bf16(fmaxf(o0, 0.f), fmaxf(o1, 0.f));
            orr.y = pk_bf16(fmaxf(o2, 0.f), fmaxf(o3, 0.f));
            *(uint2*)&hrout[rbase + (size_t)(px + 1) * CPAD + c0] = orr;
        }
    }
}

// MFMA gated block conv, 32x32x16. grid (64,16) = (y,b), block 320 (5 waves).
// Wave w: m-tile0 = a-ch [32w,32w+32), m-tile1 = gate-ch [160+32w, ..). N=64.
// Per-wave tap rotation + manual A prefetch + epilogue residual prefetch.
__global__ __launch_bounds__(320, 3) void k_blk(const unsigned short* __restrict__ h_in,
                                                unsigned short* __restrict__ h_out,
                                                const unsigned short* __restrict__ hr_in,
                                                unsigned short* __restrict__ hr_out,
                                                const short* __restrict__ wP) {
    __shared__ short in_s[2 * RST];   // rows yp=y, y+1 (data y-1, y) = 44352 B
    int y = blockIdx.x, b = blockIdx.y;
    int t = threadIdx.x;
    int lane = t & 63, w = t >> 6;
    // async contiguous copy: hrelu rows yp=y .. y+1 (2*11088 elem = 2772 x 16B)
    {
        const unsigned short* src = hr_in + ((size_t)b * 65 + y) * RST;
        #pragma unroll
        for (int r = 0; r < 9; ++r) {
            int cb = __builtin_amdgcn_readfirstlane(r * 320 + w * 64);
            if (cb + lane < 2772) {
                __builtin_amdgcn_global_load_lds(
                    (const __attribute__((address_space(1))) unsigned int*)(src + (size_t)(cb + lane) * 8),
                    (__attribute__((address_space(3))) unsigned int*)(in_s + cb * 8),
                    16, 0, 0);
            }
        }
    }
    int lm = lane & 31, pair = lane >> 5;
    // prefetch epilogue residual reads (independent of k-loop)
    size_t rowbase = ((size_t)(b * 64 + y)) * 64 * 160;
    ushort4 hv[2][4];
    #pragma unroll
    for (int n = 0; n < 2; ++n) {
        int px = n * 32 + lm;
        #pragma unroll
        for (int qd = 0; qd < 4; ++qd) {
            int c0 = 32 * w + qd * 8 + 4 * pair;
            hv[n][qd] = *(const ushort4*)&h_in[rowbase + (size_t)px * 160 + c0];
        }
    }
    __syncthreads();

    f32x16 acc[2][2] = {};   // [a/gate][n-tile]
    const short* waP = wP + pair * 2560 + (32 * w + lm) * 8;
    const int dxs[5] = {-1, 0, 1, -1, 0};
    const int rws[5] = {0, 0, 0, 1, 1};
    #pragma unroll
    for (int tt = 0; tt < 5; ++tt) {
        int tap = tt + w;  tap = (tap >= 5) ? tap - 5 : tap;   // per-wave rotation
        int rb0 = (rws[tap] * 66 + 1 + dxs[tap] + lm) * CPAD + pair * 8;
        int s0 = tap * 10;
        short8 pA = *(const short8*)(waP + (size_t)s0 * 5120);
        short8 pG = *(const short8*)(waP + 1280 + (size_t)s0 * 5120);
        #pragma unroll
        for (int si = 0; si < 10; ++si) {
            short8 aA = pA, aG = pG;
            if (si < 9) {
                pA = *(const short8*)(waP + (size_t)(s0 + si + 1) * 5120);
                pG = *(const short8*)(waP + 1280 + (size_t)(s0 + si + 1) * 5120);
            }
            short8 b0 = *(const short8*)&in_s[rb0 + si * 16];
            short8 b1 = *(const short8*)&in_s[rb0 + 32 * CPAD + si * 16];
            acc[0][0] = __builtin_amdgcn_mfma_f32_32x32x16_bf16(aA, b0, acc[0][0], 0, 0, 0);
            acc[0][1] = __builtin_amdgcn_mfma_f32_32x32x16_bf16(aA, b1, acc[0][1], 0, 0, 0);
            acc[1][0] = __builtin_amdgcn_mfma_f32_32x32x16_bf16(aG, b0, acc[1][0], 0, 0, 0);
            acc[1][1] = __builtin_amdgcn_mfma_f32_32x32x16_bf16(aG, b1, acc[1][1], 0, 0, 0);
        }
    }
    // epilogue: C layout col=lane&31(px), row=(reg&3)+8*(reg>>2)+4*pair (oc)
    size_t rbase = ((size_t)b * 65 + (y + 1)) * RST;
    #pragma unroll
    for (int n = 0; n < 2; ++n) {
        int px = n * 32 + lm;
        #pragma unroll
        for (int qd = 0; qd < 4; ++qd) {
            int c0 = 32 * w + qd * 8 + 4 * pair;
            size_t offh = rowbase + (size_t)px * 160 + c0;
            float o0 = bf2f(hv[n][qd].x) + ftanh(acc[0][n][qd * 4 + 0]) * fsigmoid(acc[1][n][qd * 4 + 0]);
            float o1 = bf2f(hv[n][qd].y) + ftanh(acc[0][n][qd * 4 + 1]) * fsigmoid(acc[1][n][qd * 4 + 1]);
            float o2 = bf2f(hv[n][qd].z) + ftanh(acc[0][n][qd * 4 + 2]) * fsigmoid(acc[1][n][qd * 4 + 2]);
            float o3 = bf2f(hv[n][qd].w) + ftanh(acc[0][n][qd * 4 + 3]) * fsigmoid(acc[1][n][qd * 4 + 3]);
            uint2 oh;
            oh.x = pk_bf16(o0, o1); oh.y = pk_bf16(o2, o3);
            *(uint2*)&h_out[offh] = oh;
            uint2 orr;
            orr.x = pk_bf16(fmaxf(o0, 0.f), fmaxf(o1, 0.f));
            orr.y = pk_bf16(fmaxf(o2, 0.f), fmaxf(o3, 0.f));
            *(uint2*)&hr_out[rbase + (size_t)(px + 1) * CPAD + c0] = orr;
        }
    }
}

// fused head: conv1x1(W1)+relu -> conv1x1(W2) -> DMOL -> atomicAdd.
// grid (128,16) = (y*2+half, b), block 320. Reads hrelu; samples 2s-1 inline.
__global__ __launch_bounds__(320) void k_head(const unsigned short* __restrict__ hr,
                                              const short* __restrict__ W1P,
                                              const short* __restrict__ W2P,
                                              const float* __restrict__ S,
                                              float* __restrict__ out) {
    __shared__ char arena[14848];         // hls(10752) aliased by Pls(13312)+lpls(1536)
    __shared__ short h2ls[32 * 168];
    short* hls = (short*)arena;           // [px32][ic pad168] bf16 relu(h)
    float* Pls = (float*)arena;           // [px32][c pad104] fp32 params
    float* lpls = (float*)(arena + 13312);// [px32][m pad12]
    int y = blockIdx.x >> 1, half = blockIdx.x & 1, b = blockIdx.y;
    int xbase = half * 32;
    int t = threadIdx.x;
    size_t rbase = ((size_t)b * 65 + (y + 1)) * RST;
    for (int i = t; i < 640; i += 320) {
        int c8 = i % 20; int px = i / 20;
        uint4 v = *(const uint4*)&hr[rbase + (size_t)(xbase + px + 1) * CPAD + c8 * 8];
        *(uint4*)&hls[px * 168 + c8 * 8] = v;
    }
    __syncthreads();
    int lane = t & 63, w = t >> 6;
    int lx = lane & 15, q = lane >> 4;
    // GEMM1: h2 = relu(W1 * hrelu)
    {
        f32x4 acc[2][2] = {};
        const short* wl = W1P + lx * 32 + q * 8;
        #pragma unroll
        for (int kc = 0; kc < 5; ++kc) {
            short8 aF[2], bF[2];
            aF[0] = *(const short8*)(wl + (kc * 160 + 32 * w) * 32);
            aF[1] = *(const short8*)(wl + (kc * 160 + 32 * w + 16) * 32);
            #pragma unroll
            for (int nt = 0; nt < 2; ++nt)
                bF[nt] = *(const short8*)&hls[(nt * 16 + lx) * 168 + kc * 32 + q * 8];
            #pragma unroll
            for (int mt = 0; mt < 2; ++mt)
                #pragma unroll
                for (int nt = 0; nt < 2; ++nt)
                    acc[mt][nt] = __builtin_amdgcn_mfma_f32_16x16x32_bf16(
                        aF[mt], bF[nt], acc[mt][nt], 0, 0, 0);
        }
        __syncthreads();   // hls reads done before Pls writes (alias)
        #pragma unroll
        for (int mt = 0; mt < 2; ++mt) {
            int c0 = 32 * w + mt * 16 + q * 4;
            #pragma unroll
            for (int nt = 0; nt < 2; ++nt) {
                int px = nt * 16 + lx;
                union { short4v s; unsigned u[2]; } sv;
                sv.u[0] = pk_bf16(fmaxf(acc[mt][nt][0], 0.f), fmaxf(acc[mt][nt][1], 0.f));
                sv.u[1] = pk_bf16(fmaxf(acc[mt][nt][2], 0.f), fmaxf(acc[mt][nt][3], 0.f));
                *(short4v*)&h2ls[px * 168 + c0] = sv.s;
            }
        }
    }
    __syncthreads();
    // GEMM2: params = W2 * h2
    {
        f32x4 acc[2][2] = {};
        const short* wl = W2P + lx * 32 + q * 8;
        #pragma unroll
        for (int kc = 0; kc < 5; ++kc) {
            short8 aF[2], bF[2];
            aF[0] = *(const short8*)(wl + (kc * 160 + 32 * w) * 32);
            aF[1] = *(const short8*)(wl + (kc * 160 + 32 * w + 16) * 32);
            #pragma unroll
            for (int nt = 0; nt < 2; ++nt)
                bF[nt] = *(const short8*)&h2ls[(nt * 16 + lx) * 168 + kc * 32 + q * 8];
            #pragma unroll
            for (int mt = 0; mt < 2; ++mt)
                #pragma unroll
                for (int nt = 0; nt < 2; ++nt)
                    acc[mt][nt] = __builtin_amdgcn_mfma_f32_16x16x32_bf16(
                        aF[mt], bF[nt], acc[mt][nt], 0, 0, 0);
        }
        #pragma unroll
        for (int mt = 0; mt < 2; ++mt) {
            int c0 = 32 * w + mt * 16 + q * 4;
            if (c0 < 100) {
                #pragma unroll
                for (int nt = 0; nt < 2; ++nt) {
                    int px = nt * 16 + lx;
                    float4 o;
                    o.x = acc[mt][nt][0]; o.y = acc[mt][nt][1];
                    o.z = acc[mt][nt][2]; o.w = acc[mt][nt][3];
                    *(float4*)&Pls[px * 104 + c0] = o;
                }
            }
        }
    }
    __syncthreads();
    // DMOL: 320 (px,m) tasks
    const float LOG127P5 = 4.8481163504f;
    {
        int px = t & 31, m = t >> 5;
        const float* pp = &Pls[px * 104];
        float xs[3];
        #pragma unroll
        for (int c = 0; c < 3; ++c)
            xs[c] = 2.f * S[((size_t)(b * 3 + c)) * 4096 + (size_t)y * 64 + xbase + px] - 1.f;
        float mx = pp[0];
        #pragma unroll
        for (int j = 1; j < 10; ++j) mx = fmaxf(mx, pp[j]);
        float se = 0.f;
        #pragma unroll
        for (int j = 0; j < 10; ++j) se += fexp(pp[j] - mx);
        float lse = mx + flog(se);
        float sum = pp[m] - lse;
        float mean0 = pp[10 + m];
        float mean1 = pp[40 + m];
        float mean2 = pp[70 + m];
        float ls0 = fmaxf(pp[20 + m], -7.f);
        float ls1 = fmaxf(pp[50 + m], -7.f);
        float ls2 = fmaxf(pp[80 + m], -7.f);
        float c0 = ftanh(pp[30 + m]);
        float c1 = ftanh(pp[60 + m]);
        float c2 = ftanh(pp[90 + m]);
        float mu[3], lsv[3];
        mu[0] = mean0;
        mu[1] = mean1 + c0 * xs[0];
        mu[2] = mean2 + c1 * xs[0] + c2 * xs[1];
        lsv[0] = ls0; lsv[1] = ls1; lsv[2] = ls2;
        #pragma unroll
        for (int ci = 0; ci < 3; ++ci) {
            float cent = xs[ci] - mu[ci];
            float inv = fexp(-lsv[ci]);
            float plus_in = inv * (cent + 1.f / 255.f);
            float min_in = inv * (cent - 1.f / 255.f);
            float cdf_delta = fsigmoid(plus_in) - fsigmoid(min_in);
            float log_cdf_plus = plus_in - fsoftplus(plus_in);
            float log_om_cdf = -fsoftplus(min_in);
            float mid = inv * cent;
            float log_pdf_mid = mid - lsv[ci] - 2.f * fsoftplus(mid);
            float lpi = (cdf_delta > 1e-5f) ? flog(fmaxf(cdf_delta, 1e-12f))
                                            : (log_pdf_mid - LOG127P5);
            float lpc = (xs[ci] < -0.999f) ? log_cdf_plus
                       : ((xs[ci] > 0.999f) ? log_om_cdf : lpi);
            sum += lpc;
        }
        lpls[px * 12 + m] = sum;
    }
    __syncthreads();
    if (t < 32) {
        int px = t;
        float mx2 = lpls[px * 12];
        #pragma unroll
        for (int m = 1; m < 10; ++m) mx2 = fmaxf(mx2, lpls[px * 12 + m]);
        float se2 = 0.f;
        #pragma unroll
        for (int m = 0; m < 10; ++m) se2 += fexp(lpls[px * 12 + m] - mx2);
        float lp = mx2 + flog(se2);
        lp += __shfl_down(lp, 16, 32);
        lp += __shfl_down(lp, 8, 32);
        lp += __shfl_down(lp, 4, 32);
        lp += __shfl_down(lp, 2, 32);
        lp += __shfl_down(lp, 1, 32);
        if (t == 0) atomicAdd(&out[b], lp);
    }
}

extern "C" void kernel_launch(void* const* d_in, const int* in_sizes, int n_in,
                              void* d_out, int out_size, void* d_ws, size_t ws_size,
                              hipStream_t stream) {
    const float* samples = (const float*)d_in[0];
    const float* w_in    = (const float*)d_in[1];
    const float* w_blk   = (const float*)d_in[2];
    const float* w_out1  = (const float*)d_in[3];
    const float* w_out2  = (const float*)d_in[4];
    char* ws = (char*)d_ws;
    short* WINP = (short*)(ws + WINP_OFF);
    short* W1P  = (short*)(ws + W1P_OFF);
    short* W2P  = (short*)(ws + W2P_OFF);
    short* WPB  = (short*)(ws + WPB_OFF);
    unsigned short* HA  = (unsigned short*)(ws + HA_OFF);
    unsigned short* HB  = (unsigned short*)(ws + HB_OFF);
    unsigned short* HRA = (unsigned short*)(ws + HRA_OFF);
    unsigned short* HRB = (unsigned short*)(ws + HRB_OFF);
    float* fout = (float*)d_out;

    k_twb<<<5000, 256, 0, stream>>>(w_blk, WPB);
    k_twin<<<60, 256, 0, stream>>>(w_in, WINP);
    k_tw1<<<100, 256, 0, stream>>>(w_out1, W1P);
    k_tw2<<<100, 256, 0, stream>>>(w_out2, W2P);
    k_halo<<<dim3((16 * 194 * CPAD + 255) / 256, 2), 256, 0, stream>>>(HRA, HRB);

    k_convin<<<dim3(128, 16), 320, 0, stream>>>(samples, WINP, HA, HRA);

    unsigned short* a = HA;  unsigned short* bq = HB;
    unsigned short* ra = HRA; unsigned short* rb = HRB;
    for (int i = 0; i < 5; i++) {
        k_blk<<<dim3(64, 16), 320, 0, stream>>>(a, bq, ra, rb, WPB + (size_t)i * 256000);
        unsigned short* tmp = a; a = bq; bq = tmp;
        unsigned short* tr = ra; ra = rb; rb = tr;
    }
    hipMemsetAsync(d_out, 0, (size_t)out_size * sizeof(float), stream);
    k_head<<<dim3(128, 16), 320, 0, stream>>>(ra, W1P, W2P, samples, fout);
}